// Round 1
// baseline (1645.381 us; speedup 1.0000x reference)
//
#include <hip/hip_runtime.h>
#include <hip/hip_bf16.h>
#include <math.h>

// Dims (fixed by the problem)
#define T_LEN 32
#define BATCH 16
#define DDIM  512
#define HDIM  512
#define EDIM  512
#define CDIM  512
#define FHH   8
#define FWW   32
#define HW    256         // FHH*FWW
#define G4    2048        // 4*HDIM
#define PADH  10
#define PADW  34
#define PLANE 340         // PADH*PADW

// ---------------------------------------------------------------------------
// Prep kernels
// ---------------------------------------------------------------------------

// conv_f (B,C,8,32) -> zero-padded (B,C,10,34)
__global__ void pad_conv(const float* __restrict__ src, float* __restrict__ dst) {
    int idx = blockIdx.x * 256 + threadIdx.x;
    const int total = BATCH * CDIM * PLANE;
    if (idx >= total) return;
    int x = idx % PADW;
    int t = idx / PADW;
    int y = t % PADH; t /= PADH;
    int c = t % CDIM;
    int b = t / CDIM;
    float v = 0.f;
    int yy = y - 1, xx = x - 1;
    if (yy >= 0 && yy < FHH && xx >= 0 && xx < FWW)
        v = src[((b * CDIM + c) * FHH + yy) * FWW + xx];
    dst[idx] = v;
}

// src (R, C) -> dst (C, R)
__global__ void transpose_k(const float* __restrict__ src, float* __restrict__ dst,
                            int R, int Ccols) {
    __shared__ float tile[32][33];
    int r0 = blockIdx.y * 32, c0 = blockIdx.x * 32;
    int tx = threadIdx.x & 31, ty = threadIdx.x >> 5;  // 256 threads, ty 0..7
    for (int i = ty; i < 32; i += 8) {
        int r = r0 + i, c = c0 + tx;
        tile[i][tx] = (r < R && c < Ccols) ? src[r * Ccols + c] : 0.f;
    }
    __syncthreads();
    for (int i = ty; i < 32; i += 8) {
        int c = c0 + i, r = r0 + tx;
        if (c < Ccols && r < R) dst[c * R + r] = tile[tx][i];
    }
}

// W_em (E,C,3,3) -> Wt (9, E, C)
__global__ void repack_wem(const float* __restrict__ src, float* __restrict__ dst) {
    int idx = blockIdx.x * 256 + threadIdx.x;
    const int total = 9 * EDIM * CDIM;
    if (idx >= total) return;
    int c = idx % CDIM;
    int t = idx / CDIM;
    int e = t % EDIM;
    int tap = t / EDIM;
    int dy = tap / 3, dx = tap % 3;
    dst[idx] = src[((e * CDIM + c) * 3 + dy) * 3 + dx];
}

// ---------------------------------------------------------------------------
// Generic fp32 tiled GEMM: C(M,N) = A(M,K) @ B(N,K)^T + bias0 + bias1
// BM=BN=64, BK=16, 256 threads, 4x4 micro-tile. M,N multiples of 64; K of 16.
// ---------------------------------------------------------------------------
__global__ __launch_bounds__(256) void gemm_bt(
    const float* __restrict__ A, const float* __restrict__ B,
    const float* __restrict__ bias0, const float* __restrict__ bias1,
    float* __restrict__ C, int M, int N, int K) {
    __shared__ float As[16][68];
    __shared__ float Bs[16][68];
    int n0 = blockIdx.x * 64, m0 = blockIdx.y * 64;
    int tid = threadIdx.x;
    int tm = tid & 15, tn = tid >> 4;
    int lr = tid >> 2;          // 0..63 (row within tile)
    int lk = (tid & 3) * 4;     // 0,4,8,12
    float acc[4][4] = {};
    for (int kk = 0; kk < K; kk += 16) {
        float4 av = *(const float4*)&A[(size_t)(m0 + lr) * K + kk + lk];
        float4 bv = *(const float4*)&B[(size_t)(n0 + lr) * K + kk + lk];
        __syncthreads();
        As[lk + 0][lr] = av.x; As[lk + 1][lr] = av.y;
        As[lk + 2][lr] = av.z; As[lk + 3][lr] = av.w;
        Bs[lk + 0][lr] = bv.x; Bs[lk + 1][lr] = bv.y;
        Bs[lk + 2][lr] = bv.z; Bs[lk + 3][lr] = bv.w;
        __syncthreads();
#pragma unroll
        for (int k = 0; k < 16; ++k) {
            float a[4], b[4];
            *(float4*)a = *(const float4*)&As[k][tm * 4];
            *(float4*)b = *(const float4*)&Bs[k][tn * 4];
#pragma unroll
            for (int i = 0; i < 4; ++i)
#pragma unroll
                for (int j = 0; j < 4; ++j) acc[i][j] += a[i] * b[j];
        }
    }
#pragma unroll
    for (int i = 0; i < 4; ++i) {
        int m = m0 + tm * 4 + i;
#pragma unroll
        for (int j = 0; j < 4; ++j) {
            int n = n0 + tn * 4 + j;
            float v = acc[i][j];
            if (bias0) v += bias0[n];
            if (bias1) v += bias1[n];
            C[(size_t)m * N + n] = v;
        }
    }
}

// ---------------------------------------------------------------------------
// conv_em as implicit GEMM over 9 taps.
// x_em[b,e,s] = b_em[e] + sum_tap sum_c pad[b,c,y+dy,x+dx] * Wt[tap,e,c]
// M = B*HW = 4096 (tiles of 64 = 2 y-rows x 32 x), N = E = 512.
// ---------------------------------------------------------------------------
__global__ __launch_bounds__(256) void conv3x3(
    const float* __restrict__ pad,   // (B,C,10,34)
    const float* __restrict__ Wt,    // (9,E,C)
    const float* __restrict__ bias,  // (E)
    float* __restrict__ xem) {       // (B,E,256)
    __shared__ float As[16][68];
    __shared__ float Bs[16][68];
    int n0 = blockIdx.x * 64;
    int m0 = blockIdx.y * 64;
    int b  = m0 >> 8;
    int s0 = m0 & 255;
    int y0 = s0 >> 5;
    int tid = threadIdx.x;
    int tm = tid & 15, tn = tid >> 4;
    int mm = tid & 63, cg = tid >> 6;        // A loader
    int y = y0 + (mm >> 5), x = mm & 31;
    int nr = tid >> 2, ck4 = (tid & 3) * 4;  // B loader
    float acc[4][4] = {};
    const float* padb = pad + (size_t)b * CDIM * PLANE;
    for (int tap = 0; tap < 9; ++tap) {
        int dy = tap / 3, dx = tap % 3;
        const float* ap = padb + (y + dy) * PADW + (x + dx);
        const float* wp = Wt + (size_t)tap * EDIM * CDIM;
        for (int kk = 0; kk < CDIM; kk += 16) {
            float a[4];
#pragma unroll
            for (int j = 0; j < 4; ++j)
                a[j] = ap[(size_t)(kk + cg * 4 + j) * PLANE];
            float4 bv = *(const float4*)&wp[(size_t)(n0 + nr) * CDIM + kk + ck4];
            __syncthreads();
#pragma unroll
            for (int j = 0; j < 4; ++j) As[cg * 4 + j][mm] = a[j];
            Bs[ck4 + 0][nr] = bv.x; Bs[ck4 + 1][nr] = bv.y;
            Bs[ck4 + 2][nr] = bv.z; Bs[ck4 + 3][nr] = bv.w;
            __syncthreads();
#pragma unroll
            for (int k = 0; k < 16; ++k) {
                float aa[4], bb[4];
                *(float4*)aa = *(const float4*)&As[k][tm * 4];
                *(float4*)bb = *(const float4*)&Bs[k][tn * 4];
#pragma unroll
                for (int i = 0; i < 4; ++i)
#pragma unroll
                    for (int j = 0; j < 4; ++j) acc[i][j] += aa[i] * bb[j];
            }
        }
    }
#pragma unroll
    for (int i = 0; i < 4; ++i) {
        int m = m0 + tm * 4 + i;
        int s = m & 255;
#pragma unroll
        for (int j = 0; j < 4; ++j) {
            int e = n0 + tn * 4 + j;
            xem[((size_t)b * EDIM + e) * HW + s] = acc[i][j] + bias[e];
        }
    }
}

// ---------------------------------------------------------------------------
// One LSTM timestep, both directions. Gates fused.
// grid: (8 j-tiles, 4 b-groups, 2 dirs), 256 threads.
// gx already contains b_ih + b_hh.
// ---------------------------------------------------------------------------
__global__ __launch_bounds__(256) void lstm_step(
    const float* __restrict__ WhhT_f, const float* __restrict__ WhhT_b,  // (512,2048)
    const float* __restrict__ gx_f, const float* __restrict__ gx_b,      // (T,B,2048)
    float* __restrict__ hs_cat,   // (T,B,1024)
    float* __restrict__ c_state,  // (2,B,512)
    int step) {
    int dir = blockIdx.z;
    int b0 = blockIdx.y * 4;
    int j0 = blockIdx.x * 64;
    int tid = threadIdx.x;
    int jj = tid & 63, bq = tid >> 6;
    int b = b0 + bq, j = j0 + jj;
    int tcur = dir ? (T_LEN - 1 - step) : step;
    const float* WhhT = dir ? WhhT_b : WhhT_f;
    const float* gx   = dir ? gx_b   : gx_f;
    __shared__ float hl[4][512];
    float ai = 0.f, af = 0.f, ag = 0.f, ao = 0.f;
    if (step > 0) {
        int tprev = dir ? tcur + 1 : tcur - 1;
        const float* hp = hs_cat + (size_t)tprev * BATCH * 1024 + dir * 512;
        for (int i = tid; i < 4 * 512; i += 256) {
            int bb = i >> 9, k = i & 511;
            hl[bb][k] = hp[(size_t)(b0 + bb) * 1024 + k];
        }
        __syncthreads();
#pragma unroll 4
        for (int k = 0; k < 512; ++k) {
            float h = hl[bq][k];
            const float* wr = WhhT + (size_t)k * G4 + j;
            ai += h * wr[0];
            af += h * wr[512];
            ag += h * wr[1024];
            ao += h * wr[1536];
        }
    }
    const float* gxr = gx + ((size_t)tcur * BATCH + b) * G4 + j;
    float gi = gxr[0]    + ai;
    float gf = gxr[512]  + af;
    float gg = gxr[1024] + ag;
    float go = gxr[1536] + ao;
    float si = 1.f / (1.f + expf(-gi));
    float sf = 1.f / (1.f + expf(-gf));
    float so = 1.f / (1.f + expf(-go));
    float c_old = (step == 0) ? 0.f : c_state[((size_t)dir * BATCH + b) * 512 + j];
    float c = sf * c_old + si * tanhf(gg);
    float h = so * tanhf(c);
    c_state[((size_t)dir * BATCH + b) * 512 + j] = c;
    hs_cat[((size_t)tcur * BATCH + b) * 1024 + dir * 512 + j] = h;
}

// hidden_de (T*B,512) -> out[b][t][0:512]
__global__ void copy_de(const float* __restrict__ hid, float* __restrict__ out) {
    int idx = blockIdx.x * 256 + threadIdx.x;  // 512*512
    int c = idx & 511, m = idx >> 9;
    int t = m >> 4, b = m & 15;
    out[((size_t)(b * T_LEN + t)) * 1024 + c] = hid[idx];
}

// ---------------------------------------------------------------------------
// Attention: one block per (t,b). scores -> softmax -> weighted sum.
// b_att cancels in the softmax, omitted.
// ---------------------------------------------------------------------------
__global__ __launch_bounds__(256) void attention(
    const float* __restrict__ xem,   // (B,E,256)
    const float* __restrict__ hem,   // (T*B,E)
    const float* __restrict__ watt,  // (E)
    float* __restrict__ out) {       // (B,T,1024)
    int tb = blockIdx.x;  // t*16+b
    int t = tb >> 4, b = tb & 15;
    int tid = threadIdx.x;
    __shared__ float hl[512], wl[512], al[256], red[8];
    for (int i = tid; i < 512; i += 256) { hl[i] = hem[(size_t)tb * 512 + i]; wl[i] = watt[i]; }
    __syncthreads();
    const float* xb = xem + (size_t)b * EDIM * HW;
    // phase 1: score for hw = tid
    float sc = 0.f;
    for (int e = 0; e < 512; ++e)
        sc += tanhf(xb[(size_t)e * HW + tid] + hl[e]) * wl[e];
    // softmax over 256 positions
    float m = sc;
#pragma unroll
    for (int o = 32; o; o >>= 1) m = fmaxf(m, __shfl_xor(m, o));
    if ((tid & 63) == 0) red[tid >> 6] = m;
    __syncthreads();
    m = fmaxf(fmaxf(red[0], red[1]), fmaxf(red[2], red[3]));
    float ex = __expf(sc - m);
    float s = ex;
#pragma unroll
    for (int o = 32; o; o >>= 1) s += __shfl_xor(s, o);
    if ((tid & 63) == 0) red[4 + (tid >> 6)] = s;
    __syncthreads();
    s = red[4] + red[5] + red[6] + red[7];
    al[tid] = ex / s;
    __syncthreads();
    // phase 3: att[e] = sum_n alpha[n] * xem[b,e,n]
    float* ob = out + ((size_t)(b * T_LEN + t)) * 1024 + 512;
    for (int eo = 0; eo < 512; eo += 256) {
        int e = eo + tid;
        const float* xr = xb + (size_t)e * HW;
        float acc = 0.f;
#pragma unroll 4
        for (int n = 0; n < 256; n += 4) {
            float4 v = *(const float4*)&xr[n];
            acc += al[n] * v.x + al[n + 1] * v.y + al[n + 2] * v.z + al[n + 3] * v.w;
        }
        ob[e] = acc;
    }
}

// ---------------------------------------------------------------------------
extern "C" void kernel_launch(void* const* d_in, const int* in_sizes, int n_in,
                              void* d_out, int out_size, void* d_ws, size_t ws_size,
                              hipStream_t stream) {
    const float* hidden_en = (const float*)d_in[0];
    const float* conv_f    = (const float*)d_in[1];
    const float* W_ih_f    = (const float*)d_in[2];
    const float* W_hh_f    = (const float*)d_in[3];
    const float* b_ih_f    = (const float*)d_in[4];
    const float* b_hh_f    = (const float*)d_in[5];
    const float* W_ih_b    = (const float*)d_in[6];
    const float* W_hh_b    = (const float*)d_in[7];
    const float* b_ih_b    = (const float*)d_in[8];
    const float* b_hh_b    = (const float*)d_in[9];
    const float* W_dec     = (const float*)d_in[10];
    const float* b_dec     = (const float*)d_in[11];
    const float* W_em      = (const float*)d_in[12];
    const float* b_em      = (const float*)d_in[13];
    const float* W_hem     = (const float*)d_in[14];
    const float* b_hem     = (const float*)d_in[15];
    const float* w_att     = (const float*)d_in[16];
    float* out = (float*)d_out;

    // bump allocator over d_ws (needs ~50 MB)
    float* ws = (float*)d_ws;
    float* conv_pad  = ws; ws += BATCH * CDIM * PLANE;   // 2,785,280
    float* WhhT_f    = ws; ws += 512 * G4;               // 1,048,576
    float* WhhT_b    = ws; ws += 512 * G4;
    float* Wt        = ws; ws += 9 * EDIM * CDIM;        // 2,359,296
    float* gx_f      = ws; ws += T_LEN * BATCH * G4;     // 1,048,576
    float* gx_b      = ws; ws += T_LEN * BATCH * G4;
    float* hs_cat    = ws; ws += T_LEN * BATCH * 1024;   // 524,288
    float* c_state   = ws; ws += 2 * BATCH * 512;        // 16,384
    float* hidden_de = ws; ws += T_LEN * BATCH * 512;    // 262,144
    float* h_em      = ws; ws += T_LEN * BATCH * 512;    // 262,144
    float* x_em      = ws; ws += BATCH * EDIM * HW;      // 2,097,152

    // prep
    pad_conv<<<(BATCH * CDIM * PLANE + 255) / 256, 256, 0, stream>>>(conv_f, conv_pad);
    transpose_k<<<dim3(16, 64), 256, 0, stream>>>(W_hh_f, WhhT_f, G4, 512);
    transpose_k<<<dim3(16, 64), 256, 0, stream>>>(W_hh_b, WhhT_b, G4, 512);
    repack_wem<<<(9 * EDIM * CDIM + 255) / 256, 256, 0, stream>>>(W_em, Wt);

    // gx for both directions (bias = b_ih + b_hh folded in)
    gemm_bt<<<dim3(32, 8), 256, 0, stream>>>(hidden_en, W_ih_f, b_ih_f, b_hh_f, gx_f,
                                             512, G4, 512);
    gemm_bt<<<dim3(32, 8), 256, 0, stream>>>(hidden_en, W_ih_b, b_ih_b, b_hh_b, gx_b,
                                             512, G4, 512);

    // conv (independent of LSTM)
    conv3x3<<<dim3(8, 64), 256, 0, stream>>>(conv_pad, Wt, b_em, x_em);

    // 32 sequential LSTM steps, both directions per launch
    for (int step = 0; step < T_LEN; ++step)
        lstm_step<<<dim3(8, 4, 2), 256, 0, stream>>>(WhhT_f, WhhT_b, gx_f, gx_b,
                                                     hs_cat, c_state, step);

    // linear decode
    gemm_bt<<<dim3(8, 8), 256, 0, stream>>>(hs_cat, W_dec, b_dec, nullptr, hidden_de,
                                            512, 512, 1024);
    copy_de<<<1024, 256, 0, stream>>>(hidden_de, out);

    // h_em
    gemm_bt<<<dim3(8, 8), 256, 0, stream>>>(hidden_de, W_hem, b_hem, nullptr, h_em,
                                            512, 512, 512);

    // attention -> out[:, :, 512:]
    attention<<<512, 256, 0, stream>>>(x_em, h_em, w_att, out);
}

// Round 2
// 1435.145 us; speedup vs baseline: 1.1465x; 1.1465x over previous
//
#include <hip/hip_runtime.h>
#include <hip/hip_bf16.h>
#include <math.h>

// Dims (fixed by the problem)
#define T_LEN 32
#define BATCH 16
#define DDIM  512
#define HDIM  512
#define EDIM  512
#define CDIM  512
#define FHH   8
#define FWW   32
#define HW    256         // FHH*FWW
#define G4    2048        // 4*HDIM
#define PADH  10
#define PADW  34

typedef __attribute__((ext_vector_type(8))) short bf16x8;
typedef __attribute__((ext_vector_type(4))) float f32x4;

// round-to-nearest-even f32 -> bf16 bits
__device__ __forceinline__ ushort bfr(float x) {
    union { float f; uint32_t u; } c; c.f = x;
    uint32_t r = (c.u + 0x7FFFu + ((c.u >> 16) & 1u)) >> 16;
    return (ushort)r;
}

__device__ __forceinline__ void ld_lds16(const void* g, void* l) {
    __builtin_amdgcn_global_load_lds((const __attribute__((address_space(1))) void*)g,
                                     (__attribute__((address_space(3))) void*)l, 16, 0, 0);
}

// ---------------------------------------------------------------------------
// Prep kernels
// ---------------------------------------------------------------------------

// zero padT (B,10,34,C) bf16
__global__ void zero_padT(ushort* __restrict__ dst) {
    int i = blockIdx.x * 256 + threadIdx.x;
    const int n = BATCH * PADH * PADW * CDIM / 4;
    if (i < n) ((ushort4*)dst)[i] = make_ushort4(0, 0, 0, 0);
}

// conv_f (B,C,8,32) f32 -> padT (B,10,34,C) bf16, interior only (transpose via LDS)
__global__ __launch_bounds__(256) void fill_padT(const float* __restrict__ src,
                                                 ushort* __restrict__ dst) {
    __shared__ float tile[32][33];
    int s0 = blockIdx.x * 32, c0 = blockIdx.y * 32, b = blockIdx.z;
    int tid = threadIdx.x;
    int lo = tid & 31, hi = tid >> 5;
#pragma unroll
    for (int it = 0; it < 4; ++it) {
        int cl = hi + it * 8;
        tile[cl][lo] = src[((size_t)(b * CDIM + c0 + cl)) * HW + s0 + lo];
    }
    __syncthreads();
#pragma unroll
    for (int it = 0; it < 4; ++it) {
        int sl = hi + it * 8;
        int s = s0 + sl;
        int y = s >> 5, x = s & 31;
        dst[(((size_t)b * PADH + y + 1) * PADW + (x + 1)) * CDIM + c0 + lo] = bfr(tile[lo][sl]);
    }
}

// W_em (E,C,3,3) f32 -> Wt (9,E,C) bf16
__global__ void repack_wem(const float* __restrict__ src, ushort* __restrict__ dst) {
    int idx = blockIdx.x * 256 + threadIdx.x;
    const int total = 9 * EDIM * CDIM;
    if (idx >= total) return;
    int c = idx % CDIM;
    int t = idx / CDIM;
    int e = t % EDIM;
    int tap = t / EDIM;
    int dy = tap / 3, dx = tap % 3;
    dst[idx] = bfr(src[((e * CDIM + c) * 3 + dy) * 3 + dx]);
}

// src (R, C) f32 -> dst (C, R) f32
__global__ void transpose_k(const float* __restrict__ src, float* __restrict__ dst,
                            int R, int Ccols) {
    __shared__ float tile[32][33];
    int r0 = blockIdx.y * 32, c0 = blockIdx.x * 32;
    int tx = threadIdx.x & 31, ty = threadIdx.x >> 5;
    for (int i = ty; i < 32; i += 8) {
        int r = r0 + i, c = c0 + tx;
        tile[i][tx] = (r < R && c < Ccols) ? src[r * Ccols + c] : 0.f;
    }
    __syncthreads();
    for (int i = ty; i < 32; i += 8) {
        int c = c0 + i, r = r0 + tx;
        if (c < Ccols && r < R) dst[c * R + r] = tile[tx][i];
    }
}

// f32 -> bf16 bits, vectorized x4
__global__ void f2b4(const float* __restrict__ s, ushort* __restrict__ d, int n4) {
    int i = blockIdx.x * 256 + threadIdx.x;
    if (i >= n4) return;
    float4 v = ((const float4*)s)[i];
    ushort4 o;
    o.x = bfr(v.x); o.y = bfr(v.y); o.z = bfr(v.z); o.w = bfr(v.w);
    ((ushort4*)d)[i] = o;
}

// ---------------------------------------------------------------------------
// bf16 MFMA GEMM: C(M,N) = A(M,K) @ B(N,K)^T + bias0 + bias1
// 128x128 tile, BK=32, 256 threads (4 waves, each 64x64), global_load_lds.
// M,N multiples of 128; K multiple of 32. Optional bf16 copy of C.
// ---------------------------------------------------------------------------
__global__ __launch_bounds__(256) void gemm_mfma(
    const ushort* __restrict__ A, const ushort* __restrict__ B,
    const float* __restrict__ bias0, const float* __restrict__ bias1,
    float* __restrict__ C, ushort* __restrict__ Cbf, int M, int N, int K)
{
    __shared__ ushort As[4096], Bs[4096];
    const int n0 = blockIdx.x * 128, m0 = blockIdx.y * 128;
    const int tid = threadIdx.x, w = tid >> 6, lane = tid & 63;
    const int r0 = tid >> 2, c0 = (tid & 3) * 8;
    const ushort* A0 = A + (size_t)(m0 + r0) * K + c0;
    const ushort* A1 = A + (size_t)(m0 + 64 + r0) * K + c0;
    const ushort* B0 = B + (size_t)(n0 + r0) * K + c0;
    const ushort* B1 = B + (size_t)(n0 + 64 + r0) * K + c0;
    ushort* AsW0 = &As[w * 512];
    ushort* AsW1 = &As[2048 + w * 512];
    ushort* BsW0 = &Bs[w * 512];
    ushort* BsW1 = &Bs[2048 + w * 512];
    const int wm = (w >> 1) * 64, wn = (w & 1) * 64;
    const int kb = (lane >> 4) * 8, fr = lane & 15;
    f32x4 acc[4][4];
#pragma unroll
    for (int i = 0; i < 4; ++i)
#pragma unroll
        for (int j = 0; j < 4; ++j) acc[i][j] = {0.f, 0.f, 0.f, 0.f};
    for (int kk = 0; kk < K; kk += 32) {
        __syncthreads();
        ld_lds16(A0 + kk, AsW0);
        ld_lds16(A1 + kk, AsW1);
        ld_lds16(B0 + kk, BsW0);
        ld_lds16(B1 + kk, BsW1);
        __syncthreads();
        bf16x8 af[4], bg[4];
#pragma unroll
        for (int i = 0; i < 4; ++i)
            af[i] = *(const bf16x8*)&As[(wm + i * 16 + fr) * 32 + kb];
#pragma unroll
        for (int j = 0; j < 4; ++j)
            bg[j] = *(const bf16x8*)&Bs[(wn + j * 16 + fr) * 32 + kb];
#pragma unroll
        for (int i = 0; i < 4; ++i)
#pragma unroll
            for (int j = 0; j < 4; ++j)
                acc[i][j] = __builtin_amdgcn_mfma_f32_16x16x32_bf16(af[i], bg[j], acc[i][j], 0, 0, 0);
    }
    const int col = lane & 15, rq = (lane >> 4) * 4;
#pragma unroll
    for (int i = 0; i < 4; ++i) {
#pragma unroll
        for (int r = 0; r < 4; ++r) {
            int m = m0 + wm + i * 16 + rq + r;
#pragma unroll
            for (int j = 0; j < 4; ++j) {
                int n = n0 + wn + j * 16 + col;
                float v = acc[i][j][r];
                if (bias0) v += bias0[n];
                if (bias1) v += bias1[n];
                C[(size_t)m * N + n] = v;
                if (Cbf) Cbf[(size_t)m * N + n] = bfr(v);
            }
        }
    }
}

// ---------------------------------------------------------------------------
// conv_em as implicit MFMA GEMM over 9 taps.
// A row (m = b*256 + y*32 + x) for tap (dy,dx) = padT[b][y+dy][x+dx][:] (contig 512)
// B = Wt (9,E,C). Output xem (B,E,256) f32. M=4096, N=512, K=9*512.
// ---------------------------------------------------------------------------
__global__ __launch_bounds__(256) void conv_mfma(
    const ushort* __restrict__ padT, const ushort* __restrict__ Wt,
    const float* __restrict__ bias, float* __restrict__ xem)
{
    __shared__ ushort As[4096], Bs[4096];
    const int n0 = blockIdx.x * 128, m0 = blockIdx.y * 128;
    const int tid = threadIdx.x, w = tid >> 6, lane = tid & 63;
    const int r0 = tid >> 2, c0 = (tid & 3) * 8;
    // per-thread A source rows (two chunks)
    int mA0 = m0 + r0, mA1 = m0 + 64 + r0;
    int b0_ = mA0 >> 8, s0_ = mA0 & 255, y0_ = s0_ >> 5, x0_ = s0_ & 31;
    int b1_ = mA1 >> 8, s1_ = mA1 & 255, y1_ = s1_ >> 5, x1_ = s1_ & 31;
    const ushort* Abase0 = padT + (((size_t)b0_ * PADH + y0_) * PADW + x0_) * CDIM + c0;
    const ushort* Abase1 = padT + (((size_t)b1_ * PADH + y1_) * PADW + x1_) * CDIM + c0;
    const ushort* Bbase0 = Wt + (size_t)(n0 + r0) * CDIM + c0;
    const ushort* Bbase1 = Wt + (size_t)(n0 + 64 + r0) * CDIM + c0;
    ushort* AsW0 = &As[w * 512];
    ushort* AsW1 = &As[2048 + w * 512];
    ushort* BsW0 = &Bs[w * 512];
    ushort* BsW1 = &Bs[2048 + w * 512];
    const int wm = (w >> 1) * 64, wn = (w & 1) * 64;
    const int kb = (lane >> 4) * 8, fr = lane & 15;
    f32x4 acc[4][4];
#pragma unroll
    for (int i = 0; i < 4; ++i)
#pragma unroll
        for (int j = 0; j < 4; ++j) acc[i][j] = {0.f, 0.f, 0.f, 0.f};
    for (int tap = 0; tap < 9; ++tap) {
        int dy = tap / 3, dx = tap % 3;
        const ushort* a0 = Abase0 + ((size_t)dy * PADW + dx) * CDIM;
        const ushort* a1 = Abase1 + ((size_t)dy * PADW + dx) * CDIM;
        const ushort* b0 = Bbase0 + (size_t)tap * EDIM * CDIM;
        const ushort* b1 = Bbase1 + (size_t)tap * EDIM * CDIM;
        for (int kk = 0; kk < CDIM; kk += 32) {
            __syncthreads();
            ld_lds16(a0 + kk, AsW0);
            ld_lds16(a1 + kk, AsW1);
            ld_lds16(b0 + kk, BsW0);
            ld_lds16(b1 + kk, BsW1);
            __syncthreads();
            bf16x8 af[4], bg[4];
#pragma unroll
            for (int i = 0; i < 4; ++i)
                af[i] = *(const bf16x8*)&As[(wm + i * 16 + fr) * 32 + kb];
#pragma unroll
            for (int j = 0; j < 4; ++j)
                bg[j] = *(const bf16x8*)&Bs[(wn + j * 16 + fr) * 32 + kb];
#pragma unroll
            for (int i = 0; i < 4; ++i)
#pragma unroll
                for (int j = 0; j < 4; ++j)
                    acc[i][j] = __builtin_amdgcn_mfma_f32_16x16x32_bf16(af[i], bg[j], acc[i][j], 0, 0, 0);
        }
    }
    const int col = lane & 15, rq = (lane >> 4) * 4;
#pragma unroll
    for (int i = 0; i < 4; ++i) {
#pragma unroll
        for (int r = 0; r < 4; ++r) {
            int m = m0 + wm + i * 16 + rq + r;
            int b = m >> 8, s = m & 255;
#pragma unroll
            for (int j = 0; j < 4; ++j) {
                int e = n0 + wn + j * 16 + col;
                xem[((size_t)b * EDIM + e) * HW + s] = acc[i][j][r] + bias[e];
            }
        }
    }
}

// ---------------------------------------------------------------------------
// One LSTM timestep, both directions. fp32. Also emits bf16 copy of h.
// ---------------------------------------------------------------------------
__global__ __launch_bounds__(256) void lstm_step(
    const float* __restrict__ WhhT_f, const float* __restrict__ WhhT_b,  // (512,2048)
    const float* __restrict__ gx_f, const float* __restrict__ gx_b,      // (T,B,2048)
    float* __restrict__ hs_cat,   // (T,B,1024)
    ushort* __restrict__ hs_bf,   // (T,B,1024) bf16
    float* __restrict__ c_state,  // (2,B,512)
    int step) {
    int dir = blockIdx.z;
    int b0 = blockIdx.y * 4;
    int j0 = blockIdx.x * 64;
    int tid = threadIdx.x;
    int jj = tid & 63, bq = tid >> 6;
    int b = b0 + bq, j = j0 + jj;
    int tcur = dir ? (T_LEN - 1 - step) : step;
    const float* WhhT = dir ? WhhT_b : WhhT_f;
    const float* gx   = dir ? gx_b   : gx_f;
    __shared__ float hl[4][512];
    float ai = 0.f, af = 0.f, ag = 0.f, ao = 0.f;
    if (step > 0) {
        int tprev = dir ? tcur + 1 : tcur - 1;
        const float* hp = hs_cat + (size_t)tprev * BATCH * 1024 + dir * 512;
        for (int i = tid; i < 4 * 512; i += 256) {
            int bb = i >> 9, k = i & 511;
            hl[bb][k] = hp[(size_t)(b0 + bb) * 1024 + k];
        }
        __syncthreads();
#pragma unroll 4
        for (int k = 0; k < 512; ++k) {
            float h = hl[bq][k];
            const float* wr = WhhT + (size_t)k * G4 + j;
            ai += h * wr[0];
            af += h * wr[512];
            ag += h * wr[1024];
            ao += h * wr[1536];
        }
    }
    const float* gxr = gx + ((size_t)tcur * BATCH + b) * G4 + j;
    float gi = gxr[0]    + ai;
    float gf = gxr[512]  + af;
    float gg = gxr[1024] + ag;
    float go = gxr[1536] + ao;
    float si = 1.f / (1.f + expf(-gi));
    float sf = 1.f / (1.f + expf(-gf));
    float so = 1.f / (1.f + expf(-go));
    float c_old = (step == 0) ? 0.f : c_state[((size_t)dir * BATCH + b) * 512 + j];
    float c = sf * c_old + si * tanhf(gg);
    float h = so * tanhf(c);
    c_state[((size_t)dir * BATCH + b) * 512 + j] = c;
    size_t oi = ((size_t)tcur * BATCH + b) * 1024 + dir * 512 + j;
    hs_cat[oi] = h;
    hs_bf[oi] = bfr(h);
}

// hidden_de (T*B,512) -> out[b][t][0:512]
__global__ void copy_de(const float* __restrict__ hid, float* __restrict__ out) {
    int idx = blockIdx.x * 256 + threadIdx.x;  // 512*512
    int c = idx & 511, m = idx >> 9;
    int t = m >> 4, b = m & 15;
    out[((size_t)(b * T_LEN + t)) * 1024 + c] = hid[idx];
}

// ---------------------------------------------------------------------------
// Attention: one block per (t,b). scores -> softmax -> weighted sum.
// ---------------------------------------------------------------------------
__global__ __launch_bounds__(256) void attention(
    const float* __restrict__ xem,   // (B,E,256)
    const float* __restrict__ hem,   // (T*B,E)
    const float* __restrict__ watt,  // (E)
    float* __restrict__ out) {       // (B,T,1024)
    int tb = blockIdx.x;  // t*16+b
    int t = tb >> 4, b = tb & 15;
    int tid = threadIdx.x;
    __shared__ float hl[512], wl[512], al[256], red[8];
    for (int i = tid; i < 512; i += 256) { hl[i] = hem[(size_t)tb * 512 + i]; wl[i] = watt[i]; }
    __syncthreads();
    const float* xb = xem + (size_t)b * EDIM * HW;
    float sc = 0.f;
    for (int e = 0; e < 512; ++e)
        sc += tanhf(xb[(size_t)e * HW + tid] + hl[e]) * wl[e];
    float m = sc;
#pragma unroll
    for (int o = 32; o; o >>= 1) m = fmaxf(m, __shfl_xor(m, o));
    if ((tid & 63) == 0) red[tid >> 6] = m;
    __syncthreads();
    m = fmaxf(fmaxf(red[0], red[1]), fmaxf(red[2], red[3]));
    float ex = __expf(sc - m);
    float s = ex;
#pragma unroll
    for (int o = 32; o; o >>= 1) s += __shfl_xor(s, o);
    if ((tid & 63) == 0) red[4 + (tid >> 6)] = s;
    __syncthreads();
    s = red[4] + red[5] + red[6] + red[7];
    al[tid] = ex / s;
    __syncthreads();
    float* ob = out + ((size_t)(b * T_LEN + t)) * 1024 + 512;
    for (int eo = 0; eo < 512; eo += 256) {
        int e = eo + tid;
        const float* xr = xb + (size_t)e * HW;
        float acc = 0.f;
#pragma unroll 4
        for (int n = 0; n < 256; n += 4) {
            float4 v = *(const float4*)&xr[n];
            acc += al[n] * v.x + al[n + 1] * v.y + al[n + 2] * v.z + al[n + 3] * v.w;
        }
        ob[e] = acc;
    }
}

// ---------------------------------------------------------------------------
extern "C" void kernel_launch(void* const* d_in, const int* in_sizes, int n_in,
                              void* d_out, int out_size, void* d_ws, size_t ws_size,
                              hipStream_t stream) {
    const float* hidden_en = (const float*)d_in[0];
    const float* conv_f    = (const float*)d_in[1];
    const float* W_ih_f    = (const float*)d_in[2];
    const float* W_hh_f    = (const float*)d_in[3];
    const float* b_ih_f    = (const float*)d_in[4];
    const float* b_hh_f    = (const float*)d_in[5];
    const float* W_ih_b    = (const float*)d_in[6];
    const float* W_hh_b    = (const float*)d_in[7];
    const float* b_ih_b    = (const float*)d_in[8];
    const float* b_hh_b    = (const float*)d_in[9];
    const float* W_dec     = (const float*)d_in[10];
    const float* b_dec     = (const float*)d_in[11];
    const float* W_em      = (const float*)d_in[12];
    const float* b_em      = (const float*)d_in[13];
    const float* W_hem     = (const float*)d_in[14];
    const float* b_hem     = (const float*)d_in[15];
    const float* w_att     = (const float*)d_in[16];
    float* out = (float*)d_out;

    // bump allocator over d_ws (~46 MB)
    char* p = (char*)d_ws;
    auto alloc = [&](size_t bytes) { void* r = p; p += (bytes + 255) & ~(size_t)255; return r; };
    float*  WhhT_f    = (float*)alloc(512 * G4 * 4);
    float*  WhhT_b    = (float*)alloc(512 * G4 * 4);
    float*  gx_f      = (float*)alloc((size_t)T_LEN * BATCH * G4 * 4);
    float*  gx_b      = (float*)alloc((size_t)T_LEN * BATCH * G4 * 4);
    float*  hs_cat    = (float*)alloc((size_t)T_LEN * BATCH * 1024 * 4);
    float*  c_state   = (float*)alloc(2 * BATCH * 512 * 4);
    float*  hidden_de = (float*)alloc((size_t)T_LEN * BATCH * 512 * 4);
    float*  h_em      = (float*)alloc((size_t)T_LEN * BATCH * 512 * 4);
    float*  x_em      = (float*)alloc((size_t)BATCH * EDIM * HW * 4);
    ushort* padT      = (ushort*)alloc((size_t)BATCH * PADH * PADW * CDIM * 2);
    ushort* Wt        = (ushort*)alloc((size_t)9 * EDIM * CDIM * 2);
    ushort* hen_bf    = (ushort*)alloc((size_t)T_LEN * BATCH * DDIM * 2);
    ushort* Wihf_bf   = (ushort*)alloc((size_t)G4 * DDIM * 2);
    ushort* Wihb_bf   = (ushort*)alloc((size_t)G4 * DDIM * 2);
    ushort* Wdec_bf   = (ushort*)alloc((size_t)HDIM * 1024 * 2);
    ushort* Whem_bf   = (ushort*)alloc((size_t)EDIM * HDIM * 2);
    ushort* hs_bf     = (ushort*)alloc((size_t)T_LEN * BATCH * 1024 * 2);
    ushort* hde_bf    = (ushort*)alloc((size_t)T_LEN * BATCH * 512 * 2);

    // prep / conversions
    zero_padT<<<(BATCH * PADH * PADW * CDIM / 4 + 255) / 256, 256, 0, stream>>>(padT);
    fill_padT<<<dim3(8, 16, 16), 256, 0, stream>>>(conv_f, padT);
    repack_wem<<<(9 * EDIM * CDIM + 255) / 256, 256, 0, stream>>>(W_em, Wt);
    transpose_k<<<dim3(16, 64), 256, 0, stream>>>(W_hh_f, WhhT_f, G4, 512);
    transpose_k<<<dim3(16, 64), 256, 0, stream>>>(W_hh_b, WhhT_b, G4, 512);
    f2b4<<<(T_LEN * BATCH * DDIM / 4 + 255) / 256, 256, 0, stream>>>(hidden_en, hen_bf, T_LEN * BATCH * DDIM / 4);
    f2b4<<<(G4 * DDIM / 4 + 255) / 256, 256, 0, stream>>>(W_ih_f, Wihf_bf, G4 * DDIM / 4);
    f2b4<<<(G4 * DDIM / 4 + 255) / 256, 256, 0, stream>>>(W_ih_b, Wihb_bf, G4 * DDIM / 4);
    f2b4<<<(HDIM * 1024 / 4 + 255) / 256, 256, 0, stream>>>(W_dec, Wdec_bf, HDIM * 1024 / 4);
    f2b4<<<(EDIM * HDIM / 4 + 255) / 256, 256, 0, stream>>>(W_hem, Whem_bf, EDIM * HDIM / 4);

    // gx for both directions (bias = b_ih + b_hh folded in)
    gemm_mfma<<<dim3(16, 4), 256, 0, stream>>>(hen_bf, Wihf_bf, b_ih_f, b_hh_f,
                                               gx_f, nullptr, 512, G4, 512);
    gemm_mfma<<<dim3(16, 4), 256, 0, stream>>>(hen_bf, Wihb_bf, b_ih_b, b_hh_b,
                                               gx_b, nullptr, 512, G4, 512);

    // conv (independent of LSTM)
    conv_mfma<<<dim3(4, 32), 256, 0, stream>>>(padT, Wt, b_em, x_em);

    // 32 sequential LSTM steps, both directions per launch
    for (int step = 0; step < T_LEN; ++step)
        lstm_step<<<dim3(8, 4, 2), 256, 0, stream>>>(WhhT_f, WhhT_b, gx_f, gx_b,
                                                     hs_cat, hs_bf, c_state, step);

    // linear decode (emit bf16 copy for h_em GEMM)
    gemm_mfma<<<dim3(4, 4), 256, 0, stream>>>(hs_bf, Wdec_bf, b_dec, nullptr,
                                              hidden_de, hde_bf, 512, 512, 1024);
    copy_de<<<1024, 256, 0, stream>>>(hidden_de, out);

    // h_em
    gemm_mfma<<<dim3(4, 4), 256, 0, stream>>>(hde_bf, Whem_bf, b_hem, nullptr,
                                              h_em, nullptr, 512, 512, 512);

    // attention -> out[:, :, 512:]
    attention<<<512, 256, 0, stream>>>(x_em, h_em, w_att, out);
}

// Round 3
// 521.972 us; speedup vs baseline: 3.1522x; 2.7495x over previous
//
#include <hip/hip_runtime.h>
#include <hip/hip_bf16.h>
#include <math.h>

// Dims (fixed by the problem)
#define T_LEN 32
#define BATCH 16
#define DDIM  512
#define HDIM  512
#define EDIM  512
#define CDIM  512
#define FHH   8
#define FWW   32
#define HW    256         // FHH*FWW
#define G4    2048        // 4*HDIM
#define PADH  10
#define PADW  34

typedef __attribute__((ext_vector_type(8))) short bf16x8;
typedef __attribute__((ext_vector_type(4))) float f32x4;

// round-to-nearest-even f32 -> bf16 bits
__device__ __forceinline__ ushort bfr(float x) {
    union { float f; uint32_t u; } c; c.f = x;
    uint32_t r = (c.u + 0x7FFFu + ((c.u >> 16) & 1u)) >> 16;
    return (ushort)r;
}

__device__ __forceinline__ float frcp(float x) { return __builtin_amdgcn_rcpf(x); }
// fast tanh: 1 - 2/(e^{2x}+1); exact at saturation, ~1e-6 rel err interior
__device__ __forceinline__ float ftanh(float x) {
    return 1.f - 2.f * frcp(1.f + __expf(2.f * x));
}
__device__ __forceinline__ float fsig(float x) {
    return frcp(1.f + __expf(-x));
}

__device__ __forceinline__ void ld_lds16(const void* g, void* l) {
    __builtin_amdgcn_global_load_lds((const __attribute__((address_space(1))) void*)g,
                                     (__attribute__((address_space(3))) void*)l, 16, 0, 0);
}

// ---------------------------------------------------------------------------
// Prep kernels
// ---------------------------------------------------------------------------

// zero padT (B,10,34,C) bf16
__global__ void zero_padT(ushort* __restrict__ dst) {
    int i = blockIdx.x * 256 + threadIdx.x;
    const int n = BATCH * PADH * PADW * CDIM / 4;
    if (i < n) ((ushort4*)dst)[i] = make_ushort4(0, 0, 0, 0);
}

// conv_f (B,C,8,32) f32 -> padT (B,10,34,C) bf16, interior only (transpose via LDS)
__global__ __launch_bounds__(256) void fill_padT(const float* __restrict__ src,
                                                 ushort* __restrict__ dst) {
    __shared__ float tile[32][33];
    int s0 = blockIdx.x * 32, c0 = blockIdx.y * 32, b = blockIdx.z;
    int tid = threadIdx.x;
    int lo = tid & 31, hi = tid >> 5;
#pragma unroll
    for (int it = 0; it < 4; ++it) {
        int cl = hi + it * 8;
        tile[cl][lo] = src[((size_t)(b * CDIM + c0 + cl)) * HW + s0 + lo];
    }
    __syncthreads();
#pragma unroll
    for (int it = 0; it < 4; ++it) {
        int sl = hi + it * 8;
        int s = s0 + sl;
        int y = s >> 5, x = s & 31;
        dst[(((size_t)b * PADH + y + 1) * PADW + (x + 1)) * CDIM + c0 + lo] = bfr(tile[lo][sl]);
    }
}

// W_em (E,C,3,3) f32 -> Wt (9,E,C) bf16
__global__ void repack_wem(const float* __restrict__ src, ushort* __restrict__ dst) {
    int idx = blockIdx.x * 256 + threadIdx.x;
    const int total = 9 * EDIM * CDIM;
    if (idx >= total) return;
    int c = idx % CDIM;
    int t = idx / CDIM;
    int e = t % EDIM;
    int tap = t / EDIM;
    int dy = tap / 3, dx = tap % 3;
    dst[idx] = bfr(src[((e * CDIM + c) * 3 + dy) * 3 + dx]);
}

// f32 -> bf16 bits, vectorized x4
__global__ void f2b4(const float* __restrict__ s, ushort* __restrict__ d, int n4) {
    int i = blockIdx.x * 256 + threadIdx.x;
    if (i >= n4) return;
    float4 v = ((const float4*)s)[i];
    ushort4 o;
    o.x = bfr(v.x); o.y = bfr(v.y); o.z = bfr(v.z); o.w = bfr(v.w);
    ((ushort4*)d)[i] = o;
}

// ---------------------------------------------------------------------------
// bf16 MFMA GEMM: C(M,N) = A(M,K) @ B(N,K)^T + bias0 + bias1
// 128x128 tile, BK=32, 256 threads (4 waves, each 64x64), global_load_lds.
// ---------------------------------------------------------------------------
__global__ __launch_bounds__(256) void gemm_mfma(
    const ushort* __restrict__ A, const ushort* __restrict__ B,
    const float* __restrict__ bias0, const float* __restrict__ bias1,
    float* __restrict__ C, ushort* __restrict__ Cbf, int M, int N, int K)
{
    __shared__ ushort As[4096], Bs[4096];
    const int n0 = blockIdx.x * 128, m0 = blockIdx.y * 128;
    const int tid = threadIdx.x, w = tid >> 6, lane = tid & 63;
    const int r0 = tid >> 2, c0 = (tid & 3) * 8;
    const ushort* A0 = A + (size_t)(m0 + r0) * K + c0;
    const ushort* A1 = A + (size_t)(m0 + 64 + r0) * K + c0;
    const ushort* B0 = B + (size_t)(n0 + r0) * K + c0;
    const ushort* B1 = B + (size_t)(n0 + 64 + r0) * K + c0;
    ushort* AsW0 = &As[w * 512];
    ushort* AsW1 = &As[2048 + w * 512];
    ushort* BsW0 = &Bs[w * 512];
    ushort* BsW1 = &Bs[2048 + w * 512];
    const int wm = (w >> 1) * 64, wn = (w & 1) * 64;
    const int kb = (lane >> 4) * 8, fr = lane & 15;
    f32x4 acc[4][4];
#pragma unroll
    for (int i = 0; i < 4; ++i)
#pragma unroll
        for (int j = 0; j < 4; ++j) acc[i][j] = {0.f, 0.f, 0.f, 0.f};
    for (int kk = 0; kk < K; kk += 32) {
        __syncthreads();
        ld_lds16(A0 + kk, AsW0);
        ld_lds16(A1 + kk, AsW1);
        ld_lds16(B0 + kk, BsW0);
        ld_lds16(B1 + kk, BsW1);
        __syncthreads();
        bf16x8 af[4], bg[4];
#pragma unroll
        for (int i = 0; i < 4; ++i)
            af[i] = *(const bf16x8*)&As[(wm + i * 16 + fr) * 32 + kb];
#pragma unroll
        for (int j = 0; j < 4; ++j)
            bg[j] = *(const bf16x8*)&Bs[(wn + j * 16 + fr) * 32 + kb];
#pragma unroll
        for (int i = 0; i < 4; ++i)
#pragma unroll
            for (int j = 0; j < 4; ++j)
                acc[i][j] = __builtin_amdgcn_mfma_f32_16x16x32_bf16(af[i], bg[j], acc[i][j], 0, 0, 0);
    }
    const int col = lane & 15, rq = (lane >> 4) * 4;
#pragma unroll
    for (int i = 0; i < 4; ++i) {
#pragma unroll
        for (int r = 0; r < 4; ++r) {
            int m = m0 + wm + i * 16 + rq + r;
#pragma unroll
            for (int j = 0; j < 4; ++j) {
                int n = n0 + wn + j * 16 + col;
                float v = acc[i][j][r];
                if (bias0) v += bias0[n];
                if (bias1) v += bias1[n];
                C[(size_t)m * N + n] = v;
                if (Cbf) Cbf[(size_t)m * N + n] = bfr(v);
            }
        }
    }
}

// ---------------------------------------------------------------------------
// conv_em as implicit MFMA GEMM over 9 taps.
// ---------------------------------------------------------------------------
__global__ __launch_bounds__(256) void conv_mfma(
    const ushort* __restrict__ padT, const ushort* __restrict__ Wt,
    const float* __restrict__ bias, float* __restrict__ xem)
{
    __shared__ ushort As[4096], Bs[4096];
    const int n0 = blockIdx.x * 128, m0 = blockIdx.y * 128;
    const int tid = threadIdx.x, w = tid >> 6, lane = tid & 63;
    const int r0 = tid >> 2, c0 = (tid & 3) * 8;
    int mA0 = m0 + r0, mA1 = m0 + 64 + r0;
    int b0_ = mA0 >> 8, s0_ = mA0 & 255, y0_ = s0_ >> 5, x0_ = s0_ & 31;
    int b1_ = mA1 >> 8, s1_ = mA1 & 255, y1_ = s1_ >> 5, x1_ = s1_ & 31;
    const ushort* Abase0 = padT + (((size_t)b0_ * PADH + y0_) * PADW + x0_) * CDIM + c0;
    const ushort* Abase1 = padT + (((size_t)b1_ * PADH + y1_) * PADW + x1_) * CDIM + c0;
    const ushort* Bbase0 = Wt + (size_t)(n0 + r0) * CDIM + c0;
    const ushort* Bbase1 = Wt + (size_t)(n0 + 64 + r0) * CDIM + c0;
    ushort* AsW0 = &As[w * 512];
    ushort* AsW1 = &As[2048 + w * 512];
    ushort* BsW0 = &Bs[w * 512];
    ushort* BsW1 = &Bs[2048 + w * 512];
    const int wm = (w >> 1) * 64, wn = (w & 1) * 64;
    const int kb = (lane >> 4) * 8, fr = lane & 15;
    f32x4 acc[4][4];
#pragma unroll
    for (int i = 0; i < 4; ++i)
#pragma unroll
        for (int j = 0; j < 4; ++j) acc[i][j] = {0.f, 0.f, 0.f, 0.f};
    for (int tap = 0; tap < 9; ++tap) {
        int dy = tap / 3, dx = tap % 3;
        const ushort* a0 = Abase0 + ((size_t)dy * PADW + dx) * CDIM;
        const ushort* a1 = Abase1 + ((size_t)dy * PADW + dx) * CDIM;
        const ushort* b0 = Bbase0 + (size_t)tap * EDIM * CDIM;
        const ushort* b1 = Bbase1 + (size_t)tap * EDIM * CDIM;
        for (int kk = 0; kk < CDIM; kk += 32) {
            __syncthreads();
            ld_lds16(a0 + kk, AsW0);
            ld_lds16(a1 + kk, AsW1);
            ld_lds16(b0 + kk, BsW0);
            ld_lds16(b1 + kk, BsW1);
            __syncthreads();
            bf16x8 af[4], bg[4];
#pragma unroll
            for (int i = 0; i < 4; ++i)
                af[i] = *(const bf16x8*)&As[(wm + i * 16 + fr) * 32 + kb];
#pragma unroll
            for (int j = 0; j < 4; ++j)
                bg[j] = *(const bf16x8*)&Bs[(wn + j * 16 + fr) * 32 + kb];
#pragma unroll
            for (int i = 0; i < 4; ++i)
#pragma unroll
                for (int j = 0; j < 4; ++j)
                    acc[i][j] = __builtin_amdgcn_mfma_f32_16x16x32_bf16(af[i], bg[j], acc[i][j], 0, 0, 0);
        }
    }
    const int col = lane & 15, rq = (lane >> 4) * 4;
#pragma unroll
    for (int i = 0; i < 4; ++i) {
#pragma unroll
        for (int r = 0; r < 4; ++r) {
            int m = m0 + wm + i * 16 + rq + r;
            int b = m >> 8, s = m & 255;
#pragma unroll
            for (int j = 0; j < 4; ++j) {
                int e = n0 + wn + j * 16 + col;
                xem[((size_t)b * EDIM + e) * HW + s] = acc[i][j][r] + bias[e];
            }
        }
    }
}

// ---------------------------------------------------------------------------
// MFMA LSTM step: gh = h_prev @ W_hh^T for both dirs, fused activations.
// One wave per (dir, 16-wide j-tile): A frag = all 16 batch rows of h_prev,
// 4 acc frags = gates i,f,g,o. W_hh used in NATIVE (4H,H) layout (bf16).
// grid (32, 2), block 64.
// ---------------------------------------------------------------------------
__global__ __launch_bounds__(64) void lstm_mfma(
    const ushort* __restrict__ Whh_f, const ushort* __restrict__ Whh_b,  // (2048,512) bf16
    const float* __restrict__ gx_f, const float* __restrict__ gx_b,      // (T,B,2048)
    ushort* __restrict__ hs_bf,   // (T,B,1024) bf16
    float* __restrict__ c_state,  // (2,B,512)
    int step)
{
    const int dir = blockIdx.y;
    const int j0 = blockIdx.x * 16;
    const int lane = threadIdx.x;
    const int tcur = dir ? (T_LEN - 1 - step) : step;
    const ushort* W = dir ? Whh_b : Whh_f;
    const float* gx = dir ? gx_b : gx_f;
    const int fr = lane & 15, kq = lane >> 4;
    f32x4 acc[4];
#pragma unroll
    for (int g = 0; g < 4; ++g) acc[g] = {0.f, 0.f, 0.f, 0.f};
    if (step > 0) {
        int tprev = dir ? tcur + 1 : tcur - 1;
        const ushort* hp = hs_bf + ((size_t)tprev * BATCH + fr) * 1024 + dir * 512 + kq * 8;
        const ushort* wp = W + (size_t)(j0 + fr) * 512 + kq * 8;
#pragma unroll 4
        for (int kk = 0; kk < 512; kk += 32) {
            bf16x8 a = *(const bf16x8*)(hp + kk);
#pragma unroll
            for (int g = 0; g < 4; ++g) {
                bf16x8 b = *(const bf16x8*)(wp + (size_t)g * 512 * 512 + kk);
                acc[g] = __builtin_amdgcn_mfma_f32_16x16x32_bf16(a, b, acc[g], 0, 0, 0);
            }
        }
    }
    // epilogue: D row = batch = (lane>>4)*4 + r, col = j = j0 + (lane&15)
    const int j = j0 + fr, rq = kq * 4;
#pragma unroll
    for (int r = 0; r < 4; ++r) {
        int b = rq + r;
        const float* gxr = gx + ((size_t)tcur * BATCH + b) * G4 + j;
        float gi = gxr[0]    + acc[0][r];
        float gf = gxr[512]  + acc[1][r];
        float gg = gxr[1024] + acc[2][r];
        float go = gxr[1536] + acc[3][r];
        float si = fsig(gi), sf = fsig(gf), so = fsig(go);
        float c_old = (step == 0) ? 0.f : c_state[((size_t)dir * BATCH + b) * 512 + j];
        float c = sf * c_old + si * ftanh(gg);
        float h = so * ftanh(c);
        c_state[((size_t)dir * BATCH + b) * 512 + j] = c;
        hs_bf[((size_t)tcur * BATCH + b) * 1024 + dir * 512 + j] = bfr(h);
    }
}

// hidden_de (T*B,512) -> out[b][t][0:512]
__global__ void copy_de(const float* __restrict__ hid, float* __restrict__ out) {
    int idx = blockIdx.x * 256 + threadIdx.x;  // 512*512
    int c = idx & 511, m = idx >> 9;
    int t = m >> 4, b = m & 15;
    out[((size_t)(b * T_LEN + t)) * 1024 + c] = hid[idx];
}

// ---------------------------------------------------------------------------
// Attention: one block per (t,b); XCD-swizzled so each XCD's L2 holds only
// 2 batch-slices of x_em. Fast tanh. scores -> softmax -> weighted sum.
// ---------------------------------------------------------------------------
__global__ __launch_bounds__(256) void attention(
    const float* __restrict__ xem,   // (B,E,256)
    const float* __restrict__ hem,   // (T*B,E)
    const float* __restrict__ watt,  // (E)
    float* __restrict__ out) {       // (B,T,1024)
    // block i -> XCD i%8 (round-robin). Decode so b>>1 == XCD id.
    int i = blockIdx.x;
    int k = i >> 3;
    int b = ((i & 7) << 1) | (k & 1);
    int t = k >> 1;
    int tb = t * 16 + b;
    int tid = threadIdx.x;
    __shared__ float hl[512], wl[512], al[256], red[8];
    for (int q = tid; q < 512; q += 256) { hl[q] = hem[(size_t)tb * 512 + q]; wl[q] = watt[q]; }
    __syncthreads();
    const float* xb = xem + (size_t)b * EDIM * HW;
    float sc = 0.f;
#pragma unroll 4
    for (int e = 0; e < 512; ++e)
        sc += ftanh(xb[(size_t)e * HW + tid] + hl[e]) * wl[e];
    float m = sc;
#pragma unroll
    for (int o = 32; o; o >>= 1) m = fmaxf(m, __shfl_xor(m, o));
    if ((tid & 63) == 0) red[tid >> 6] = m;
    __syncthreads();
    m = fmaxf(fmaxf(red[0], red[1]), fmaxf(red[2], red[3]));
    float ex = __expf(sc - m);
    float s = ex;
#pragma unroll
    for (int o = 32; o; o >>= 1) s += __shfl_xor(s, o);
    if ((tid & 63) == 0) red[4 + (tid >> 6)] = s;
    __syncthreads();
    s = red[4] + red[5] + red[6] + red[7];
    al[tid] = ex * frcp(s);
    __syncthreads();
    float* ob = out + ((size_t)(b * T_LEN + t)) * 1024 + 512;
    for (int eo = 0; eo < 512; eo += 256) {
        int e = eo + tid;
        const float* xr = xb + (size_t)e * HW;
        float acc = 0.f;
#pragma unroll 4
        for (int n = 0; n < 256; n += 4) {
            float4 v = *(const float4*)&xr[n];
            acc += al[n] * v.x + al[n + 1] * v.y + al[n + 2] * v.z + al[n + 3] * v.w;
        }
        ob[e] = acc;
    }
}

// ---------------------------------------------------------------------------
extern "C" void kernel_launch(void* const* d_in, const int* in_sizes, int n_in,
                              void* d_out, int out_size, void* d_ws, size_t ws_size,
                              hipStream_t stream) {
    const float* hidden_en = (const float*)d_in[0];
    const float* conv_f    = (const float*)d_in[1];
    const float* W_ih_f    = (const float*)d_in[2];
    const float* W_hh_f    = (const float*)d_in[3];
    const float* b_ih_f    = (const float*)d_in[4];
    const float* b_hh_f    = (const float*)d_in[5];
    const float* W_ih_b    = (const float*)d_in[6];
    const float* W_hh_b    = (const float*)d_in[7];
    const float* b_ih_b    = (const float*)d_in[8];
    const float* b_hh_b    = (const float*)d_in[9];
    const float* W_dec     = (const float*)d_in[10];
    const float* b_dec     = (const float*)d_in[11];
    const float* W_em      = (const float*)d_in[12];
    const float* b_em      = (const float*)d_in[13];
    const float* W_hem     = (const float*)d_in[14];
    const float* b_hem     = (const float*)d_in[15];
    const float* w_att     = (const float*)d_in[16];
    float* out = (float*)d_out;

    // bump allocator over d_ws
    char* p = (char*)d_ws;
    auto alloc = [&](size_t bytes) { void* r = p; p += (bytes + 255) & ~(size_t)255; return r; };
    float*  gx_f      = (float*)alloc((size_t)T_LEN * BATCH * G4 * 4);
    float*  gx_b      = (float*)alloc((size_t)T_LEN * BATCH * G4 * 4);
    float*  c_state   = (float*)alloc(2 * BATCH * 512 * 4);
    float*  hidden_de = (float*)alloc((size_t)T_LEN * BATCH * 512 * 4);
    float*  h_em      = (float*)alloc((size_t)T_LEN * BATCH * 512 * 4);
    float*  x_em      = (float*)alloc((size_t)BATCH * EDIM * HW * 4);
    ushort* padT      = (ushort*)alloc((size_t)BATCH * PADH * PADW * CDIM * 2);
    ushort* Wt        = (ushort*)alloc((size_t)9 * EDIM * CDIM * 2);
    ushort* hen_bf    = (ushort*)alloc((size_t)T_LEN * BATCH * DDIM * 2);
    ushort* Wihf_bf   = (ushort*)alloc((size_t)G4 * DDIM * 2);
    ushort* Wihb_bf   = (ushort*)alloc((size_t)G4 * DDIM * 2);
    ushort* Whhf_bf   = (ushort*)alloc((size_t)G4 * HDIM * 2);
    ushort* Whhb_bf   = (ushort*)alloc((size_t)G4 * HDIM * 2);
    ushort* Wdec_bf   = (ushort*)alloc((size_t)HDIM * 1024 * 2);
    ushort* Whem_bf   = (ushort*)alloc((size_t)EDIM * HDIM * 2);
    ushort* hs_bf     = (ushort*)alloc((size_t)T_LEN * BATCH * 1024 * 2);
    ushort* hde_bf    = (ushort*)alloc((size_t)T_LEN * BATCH * 512 * 2);

    // prep / conversions
    zero_padT<<<(BATCH * PADH * PADW * CDIM / 4 + 255) / 256, 256, 0, stream>>>(padT);
    fill_padT<<<dim3(8, 16, 16), 256, 0, stream>>>(conv_f, padT);
    repack_wem<<<(9 * EDIM * CDIM + 255) / 256, 256, 0, stream>>>(W_em, Wt);
    f2b4<<<256, 256, 0, stream>>>(hidden_en, hen_bf, T_LEN * BATCH * DDIM / 4);
    f2b4<<<1024, 256, 0, stream>>>(W_ih_f, Wihf_bf, G4 * DDIM / 4);
    f2b4<<<1024, 256, 0, stream>>>(W_ih_b, Wihb_bf, G4 * DDIM / 4);
    f2b4<<<1024, 256, 0, stream>>>(W_hh_f, Whhf_bf, G4 * HDIM / 4);
    f2b4<<<1024, 256, 0, stream>>>(W_hh_b, Whhb_bf, G4 * HDIM / 4);
    f2b4<<<512, 256, 0, stream>>>(W_dec, Wdec_bf, HDIM * 1024 / 4);
    f2b4<<<256, 256, 0, stream>>>(W_hem, Whem_bf, EDIM * HDIM / 4);

    // gx for both directions (bias = b_ih + b_hh folded in)
    gemm_mfma<<<dim3(16, 4), 256, 0, stream>>>(hen_bf, Wihf_bf, b_ih_f, b_hh_f,
                                               gx_f, nullptr, 512, G4, 512);
    gemm_mfma<<<dim3(16, 4), 256, 0, stream>>>(hen_bf, Wihb_bf, b_ih_b, b_hh_b,
                                               gx_b, nullptr, 512, G4, 512);

    // conv (independent of LSTM)
    conv_mfma<<<dim3(4, 32), 256, 0, stream>>>(padT, Wt, b_em, x_em);

    // 32 sequential LSTM steps (both directions per launch, MFMA recurrence)
    for (int step = 0; step < T_LEN; ++step)
        lstm_mfma<<<dim3(32, 2), 64, 0, stream>>>(Whhf_bf, Whhb_bf, gx_f, gx_b,
                                                  hs_bf, c_state, step);

    // linear decode (emit bf16 copy for h_em GEMM)
    gemm_mfma<<<dim3(4, 4), 256, 0, stream>>>(hs_bf, Wdec_bf, b_dec, nullptr,
                                              hidden_de, hde_bf, 512, 512, 1024);
    copy_de<<<1024, 256, 0, stream>>>(hidden_de, out);

    // h_em
    gemm_mfma<<<dim3(4, 4), 256, 0, stream>>>(hde_bf, Whem_bf, b_hem, nullptr,
                                              h_em, nullptr, 512, 512, 512);

    // attention -> out[:, :, 512:]
    attention<<<512, 256, 0, stream>>>(x_em, h_em, w_att, out);
}

// Round 4
// 446.472 us; speedup vs baseline: 3.6853x; 1.1691x over previous
//
#include <hip/hip_runtime.h>
#include <hip/hip_bf16.h>
#include <math.h>

// Dims (fixed by the problem)
#define T_LEN 32
#define BATCH 16
#define DDIM  512
#define HDIM  512
#define EDIM  512
#define CDIM  512
#define FHH   8
#define FWW   32
#define HW    256         // FHH*FWW
#define G4    2048        // 4*HDIM
#define PADH  10
#define PADW  34

typedef __attribute__((ext_vector_type(8))) short bf16x8;
typedef __attribute__((ext_vector_type(4))) float f32x4;

// round-to-nearest-even f32 -> bf16 bits
__device__ __forceinline__ ushort bfr(float x) {
    union { float f; uint32_t u; } c; c.f = x;
    uint32_t r = (c.u + 0x7FFFu + ((c.u >> 16) & 1u)) >> 16;
    return (ushort)r;
}

__device__ __forceinline__ float frcp(float x) { return __builtin_amdgcn_rcpf(x); }
__device__ __forceinline__ float ftanh(float x) {
    return 1.f - 2.f * frcp(1.f + __expf(2.f * x));
}
__device__ __forceinline__ float fsig(float x) {
    return frcp(1.f + __expf(-x));
}

__device__ __forceinline__ void ld_lds16(const void* g, void* l) {
    __builtin_amdgcn_global_load_lds((const __attribute__((address_space(1))) void*)g,
                                     (__attribute__((address_space(3))) void*)l, 16, 0, 0);
}

// ---------------------------------------------------------------------------
// Prep kernels
// ---------------------------------------------------------------------------

// zero padT (B,10,34,C) bf16
__global__ void zero_padT(ushort* __restrict__ dst) {
    int i = blockIdx.x * 256 + threadIdx.x;
    const int n = BATCH * PADH * PADW * CDIM / 4;
    if (i < n) ((ushort4*)dst)[i] = make_ushort4(0, 0, 0, 0);
}

// conv_f (B,C,8,32) f32 -> padT (B,10,34,C) bf16, interior only (transpose via LDS)
__global__ __launch_bounds__(256) void fill_padT(const float* __restrict__ src,
                                                 ushort* __restrict__ dst) {
    __shared__ float tile[32][33];
    int s0 = blockIdx.x * 32, c0 = blockIdx.y * 32, b = blockIdx.z;
    int tid = threadIdx.x;
    int lo = tid & 31, hi = tid >> 5;
#pragma unroll
    for (int it = 0; it < 4; ++it) {
        int cl = hi + it * 8;
        tile[cl][lo] = src[((size_t)(b * CDIM + c0 + cl)) * HW + s0 + lo];
    }
    __syncthreads();
#pragma unroll
    for (int it = 0; it < 4; ++it) {
        int sl = hi + it * 8;
        int s = s0 + sl;
        int y = s >> 5, x = s & 31;
        dst[(((size_t)b * PADH + y + 1) * PADW + (x + 1)) * CDIM + c0 + lo] = bfr(tile[lo][sl]);
    }
}

// W_em (E,C,3,3) f32 -> Wt (9,E,C) bf16
__global__ void repack_wem(const float* __restrict__ src, ushort* __restrict__ dst) {
    int idx = blockIdx.x * 256 + threadIdx.x;
    const int total = 9 * EDIM * CDIM;
    if (idx >= total) return;
    int c = idx % CDIM;
    int t = idx / CDIM;
    int e = t % EDIM;
    int tap = t / EDIM;
    int dy = tap / 3, dx = tap % 3;
    dst[idx] = bfr(src[((e * CDIM + c) * 3 + dy) * 3 + dx]);
}

// fused f32->bf16 of 7 tensors + zero the LSTM barrier counter
struct PrepArgs { const float* s[7]; ushort* d[7]; };
__global__ void fuse_prep(PrepArgs a, unsigned* __restrict__ cnt) {
    int i = blockIdx.x * 256 + threadIdx.x;
    if (i == 0) *cnt = 0u;
    // chunk counts (float4): hen 65536 | Wihf 262144 | Wihb 262144 |
    //                        Whhf 262144 | Whhb 262144 | Wdec 131072 | Whem 65536
    const int e0 = 65536, e1 = 327680, e2 = 589824, e3 = 851968,
              e4 = 1114112, e5 = 1245184, e6 = 1310720;
    int seg, base;
    if      (i < e0) { seg = 0; base = 0;  }
    else if (i < e1) { seg = 1; base = e0; }
    else if (i < e2) { seg = 2; base = e1; }
    else if (i < e3) { seg = 3; base = e2; }
    else if (i < e4) { seg = 4; base = e3; }
    else if (i < e5) { seg = 5; base = e4; }
    else if (i < e6) { seg = 6; base = e5; }
    else return;
    int li = i - base;
    float4 v = ((const float4*)a.s[seg])[li];
    ushort4 o;
    o.x = bfr(v.x); o.y = bfr(v.y); o.z = bfr(v.z); o.w = bfr(v.w);
    ((ushort4*)a.d[seg])[li] = o;
}

// ---------------------------------------------------------------------------
// bf16 MFMA GEMM, 64x64 tile, BK=32, 256 threads (4 waves, wave-tile 32x32).
// C(M,N) = A(M,K) @ B(N,K)^T + bias0 + bias1.
// Outputs: optional f32 C, optional bf16 Cbf, optional scatter into out
// (decode mapping: row m = t*16+b -> out[(b*32+t)*1024 + n], N must be 512).
// ---------------------------------------------------------------------------
__global__ __launch_bounds__(256) void gemm64(
    const ushort* __restrict__ A, const ushort* __restrict__ B,
    const float* __restrict__ bias0, const float* __restrict__ bias1,
    float* __restrict__ C, ushort* __restrict__ Cbf, float* __restrict__ Cscat,
    int M, int N, int K)
{
    __shared__ ushort As[2048], Bs[2048];
    const int n0 = blockIdx.x * 64, m0 = blockIdx.y * 64;
    const int tid = threadIdx.x, w = tid >> 6, lane = tid & 63;
    const int r0 = tid >> 2, c0 = (tid & 3) * 8;
    const ushort* Ap = A + (size_t)(m0 + r0) * K + c0;
    const ushort* Bp = B + (size_t)(n0 + r0) * K + c0;
    ushort* AsW = &As[w * 512];
    ushort* BsW = &Bs[w * 512];
    const int wm = (w >> 1) * 32, wn = (w & 1) * 32;
    const int kb = (lane >> 4) * 8, fr = lane & 15;
    f32x4 acc[2][2];
#pragma unroll
    for (int i = 0; i < 2; ++i)
#pragma unroll
        for (int j = 0; j < 2; ++j) acc[i][j] = {0.f, 0.f, 0.f, 0.f};
    for (int kk = 0; kk < K; kk += 32) {
        __syncthreads();
        ld_lds16(Ap + kk, AsW);
        ld_lds16(Bp + kk, BsW);
        __syncthreads();
        bf16x8 af[2], bg[2];
#pragma unroll
        for (int i = 0; i < 2; ++i)
            af[i] = *(const bf16x8*)&As[(wm + i * 16 + fr) * 32 + kb];
#pragma unroll
        for (int j = 0; j < 2; ++j)
            bg[j] = *(const bf16x8*)&Bs[(wn + j * 16 + fr) * 32 + kb];
#pragma unroll
        for (int i = 0; i < 2; ++i)
#pragma unroll
            for (int j = 0; j < 2; ++j)
                acc[i][j] = __builtin_amdgcn_mfma_f32_16x16x32_bf16(af[i], bg[j], acc[i][j], 0, 0, 0);
    }
    const int col = lane & 15, rq = (lane >> 4) * 4;
#pragma unroll
    for (int i = 0; i < 2; ++i) {
#pragma unroll
        for (int r = 0; r < 4; ++r) {
            int m = m0 + wm + i * 16 + rq + r;
#pragma unroll
            for (int j = 0; j < 2; ++j) {
                int n = n0 + wn + j * 16 + col;
                float v = acc[i][j][r];
                if (bias0) v += bias0[n];
                if (bias1) v += bias1[n];
                if (C)   C[(size_t)m * N + n] = v;
                if (Cbf) Cbf[(size_t)m * N + n] = bfr(v);
                if (Cscat) {
                    int t = m >> 4, b = m & 15;
                    Cscat[((size_t)(b * T_LEN + t)) * 1024 + n] = v;
                }
            }
        }
    }
}

// ---------------------------------------------------------------------------
// conv_em implicit MFMA GEMM, 64x64 tile. grid (8, 64) = 512 blocks.
// ---------------------------------------------------------------------------
__global__ __launch_bounds__(256) void conv64(
    const ushort* __restrict__ padT, const ushort* __restrict__ Wt,
    const float* __restrict__ bias, float* __restrict__ xem)
{
    __shared__ ushort As[2048], Bs[2048];
    const int n0 = blockIdx.x * 64, m0 = blockIdx.y * 64;
    const int tid = threadIdx.x, w = tid >> 6, lane = tid & 63;
    const int r0 = tid >> 2, c0 = (tid & 3) * 8;
    const int b = m0 >> 8, s0 = m0 & 255, y0 = s0 >> 5;
    const int y = y0 + (r0 >> 5), x = r0 & 31;
    const ushort* Abase = padT + (((size_t)b * PADH + y) * PADW + x) * CDIM + c0;
    const ushort* Bbase = Wt + (size_t)(n0 + r0) * CDIM + c0;
    ushort* AsW = &As[w * 512];
    ushort* BsW = &Bs[w * 512];
    const int wm = (w >> 1) * 32, wn = (w & 1) * 32;
    const int kb = (lane >> 4) * 8, fr = lane & 15;
    f32x4 acc[2][2];
#pragma unroll
    for (int i = 0; i < 2; ++i)
#pragma unroll
        for (int j = 0; j < 2; ++j) acc[i][j] = {0.f, 0.f, 0.f, 0.f};
    for (int tap = 0; tap < 9; ++tap) {
        const int dy = tap / 3, dx = tap % 3;
        const ushort* ap = Abase + ((size_t)dy * PADW + dx) * CDIM;
        const ushort* bp = Bbase + (size_t)tap * EDIM * CDIM;
        for (int kk = 0; kk < CDIM; kk += 32) {
            __syncthreads();
            ld_lds16(ap + kk, AsW);
            ld_lds16(bp + kk, BsW);
            __syncthreads();
            bf16x8 af[2], bg[2];
#pragma unroll
            for (int i = 0; i < 2; ++i)
                af[i] = *(const bf16x8*)&As[(wm + i * 16 + fr) * 32 + kb];
#pragma unroll
            for (int j = 0; j < 2; ++j)
                bg[j] = *(const bf16x8*)&Bs[(wn + j * 16 + fr) * 32 + kb];
#pragma unroll
            for (int i = 0; i < 2; ++i)
#pragma unroll
                for (int j = 0; j < 2; ++j)
                    acc[i][j] = __builtin_amdgcn_mfma_f32_16x16x32_bf16(af[i], bg[j], acc[i][j], 0, 0, 0);
        }
    }
    const int col = lane & 15, rq = (lane >> 4) * 4;
#pragma unroll
    for (int i = 0; i < 2; ++i) {
#pragma unroll
        for (int r = 0; r < 4; ++r) {
            int m = m0 + wm + i * 16 + rq + r;
            int s = m & 255;
#pragma unroll
            for (int j = 0; j < 2; ++j) {
                int e = n0 + wn + j * 16 + col;
                xem[((size_t)b * EDIM + e) * HW + s] = acc[i][j][r] + bias[e];
            }
        }
    }
}

// ---------------------------------------------------------------------------
// Persistent LSTM: 64 blocks x 64 threads (1 wave each), all 32 steps in one
// launch with a grid-wide spin barrier. Block = (dir, 16-wide j-tile).
// W_hh slice (4 gates x 16 j x 512 k bf16 = 64KB) staged in LDS once;
// c-state lives in registers; h exchanged through global with agent fences.
// ---------------------------------------------------------------------------
__global__ __launch_bounds__(64) void lstm_persist(
    const ushort* __restrict__ Whh_f, const ushort* __restrict__ Whh_b,  // (2048,512) bf16
    const float* __restrict__ gx_f, const float* __restrict__ gx_b,      // (T,B,2048)
    ushort* __restrict__ hs_bf,     // (T,B,1024) bf16
    unsigned* __restrict__ cnt)     // barrier counter (pre-zeroed on stream)
{
    __shared__ ushort Wl[4 * 16 * 512];   // 64KB
    const int blk = blockIdx.x;
    const int dir = blk >> 5;
    const int j0 = (blk & 31) * 16;
    const int lane = threadIdx.x;
    const ushort* W = dir ? Whh_b : Whh_f;
    const float* gx = dir ? gx_b : gx_f;
    const int fr = lane & 15, kq = lane >> 4;

    // stage W slice: rows (g*16+jl) of 512 k, linear row-major in LDS
    for (int c = 0; c < 64; ++c) {
        int row = c;                       // 0..63 = g*16 + jl
        int g = row >> 4, jl = row & 15;
        bf16x8 v = *(const bf16x8*)(W + ((size_t)(g * 512 + j0 + jl)) * 512 + lane * 8);
        *(bf16x8*)((char*)Wl + (size_t)row * 1024 + lane * 16) = v;
    }
    __syncthreads();

    const int j = j0 + fr;
    f32x4 cr = {0.f, 0.f, 0.f, 0.f};
    for (int step = 0; step < T_LEN; ++step) {
        const int tcur = dir ? (T_LEN - 1 - step) : step;
        f32x4 acc[4];
#pragma unroll
        for (int g = 0; g < 4; ++g) acc[g] = {0.f, 0.f, 0.f, 0.f};
        if (step > 0) {
            const int tprev = dir ? tcur + 1 : tcur - 1;
            const ushort* hp = hs_bf + ((size_t)tprev * BATCH + fr) * 1024 + dir * 512 + kq * 8;
#pragma unroll 4
            for (int kk = 0; kk < 512; kk += 32) {
                bf16x8 a = *(const bf16x8*)(hp + kk);
#pragma unroll
                for (int g = 0; g < 4; ++g) {
                    bf16x8 bb = *(const bf16x8*)&Wl[(g * 16 + fr) * 512 + kq * 8 + kk];
                    acc[g] = __builtin_amdgcn_mfma_f32_16x16x32_bf16(a, bb, acc[g], 0, 0, 0);
                }
            }
        }
        // epilogue: batch = kq*4+r, col j
#pragma unroll
        for (int r = 0; r < 4; ++r) {
            int b = kq * 4 + r;
            const float* gxr = gx + ((size_t)tcur * BATCH + b) * G4 + j;
            float gi = gxr[0]    + acc[0][r];
            float gf = gxr[512]  + acc[1][r];
            float gg = gxr[1024] + acc[2][r];
            float go = gxr[1536] + acc[3][r];
            float si = fsig(gi), sf = fsig(gf), so = fsig(go);
            float c = sf * cr[r] + si * ftanh(gg);
            cr[r] = c;
            float h = so * ftanh(c);
            hs_bf[((size_t)tcur * BATCH + b) * 1024 + dir * 512 + j] = bfr(h);
        }
        if (step < T_LEN - 1) {
            __threadfence();                       // release h stores (agent scope)
            if (lane == 0) {
                atomicAdd(cnt, 1u);
                unsigned tgt = 64u * (unsigned)(step + 1);
                while (__hip_atomic_load(cnt, __ATOMIC_RELAXED, __HIP_MEMORY_SCOPE_AGENT) < tgt)
                    __builtin_amdgcn_s_sleep(2);
            }
            __threadfence();                       // acquire before reading h
        }
    }
}

// ---------------------------------------------------------------------------
// Attention: one block per (t,b), XCD-swizzled; fast tanh.
// ---------------------------------------------------------------------------
__global__ __launch_bounds__(256) void attention(
    const float* __restrict__ xem,   // (B,E,256)
    const float* __restrict__ hem,   // (T*B,E)
    const float* __restrict__ watt,  // (E)
    float* __restrict__ out) {       // (B,T,1024)
    int i = blockIdx.x;
    int k = i >> 3;
    int b = ((i & 7) << 1) | (k & 1);
    int t = k >> 1;
    int tb = t * 16 + b;
    int tid = threadIdx.x;
    __shared__ float hl[512], wl[512], al[256], red[8];
    for (int q = tid; q < 512; q += 256) { hl[q] = hem[(size_t)tb * 512 + q]; wl[q] = watt[q]; }
    __syncthreads();
    const float* xb = xem + (size_t)b * EDIM * HW;
    float sc = 0.f;
#pragma unroll 4
    for (int e = 0; e < 512; ++e)
        sc += ftanh(xb[(size_t)e * HW + tid] + hl[e]) * wl[e];
    float m = sc;
#pragma unroll
    for (int o = 32; o; o >>= 1) m = fmaxf(m, __shfl_xor(m, o));
    if ((tid & 63) == 0) red[tid >> 6] = m;
    __syncthreads();
    m = fmaxf(fmaxf(red[0], red[1]), fmaxf(red[2], red[3]));
    float ex = __expf(sc - m);
    float s = ex;
#pragma unroll
    for (int o = 32; o; o >>= 1) s += __shfl_xor(s, o);
    if ((tid & 63) == 0) red[4 + (tid >> 6)] = s;
    __syncthreads();
    s = red[4] + red[5] + red[6] + red[7];
    al[tid] = ex * frcp(s);
    __syncthreads();
    float* ob = out + ((size_t)(b * T_LEN + t)) * 1024 + 512;
    for (int eo = 0; eo < 512; eo += 256) {
        int e = eo + tid;
        const float* xr = xb + (size_t)e * HW;
        float acc = 0.f;
#pragma unroll 4
        for (int n = 0; n < 256; n += 4) {
            float4 v = *(const float4*)&xr[n];
            acc += al[n] * v.x + al[n + 1] * v.y + al[n + 2] * v.z + al[n + 3] * v.w;
        }
        ob[e] = acc;
    }
}

// ---------------------------------------------------------------------------
extern "C" void kernel_launch(void* const* d_in, const int* in_sizes, int n_in,
                              void* d_out, int out_size, void* d_ws, size_t ws_size,
                              hipStream_t stream) {
    const float* hidden_en = (const float*)d_in[0];
    const float* conv_f    = (const float*)d_in[1];
    const float* W_ih_f    = (const float*)d_in[2];
    const float* W_hh_f    = (const float*)d_in[3];
    const float* b_ih_f    = (const float*)d_in[4];
    const float* b_hh_f    = (const float*)d_in[5];
    const float* W_ih_b    = (const float*)d_in[6];
    const float* W_hh_b    = (const float*)d_in[7];
    const float* b_ih_b    = (const float*)d_in[8];
    const float* b_hh_b    = (const float*)d_in[9];
    const float* W_dec     = (const float*)d_in[10];
    const float* b_dec     = (const float*)d_in[11];
    const float* W_em      = (const float*)d_in[12];
    const float* b_em      = (const float*)d_in[13];
    const float* W_hem     = (const float*)d_in[14];
    const float* b_hem     = (const float*)d_in[15];
    const float* w_att     = (const float*)d_in[16];
    float* out = (float*)d_out;

    // bump allocator over d_ws (~35 MB)
    char* p = (char*)d_ws;
    auto alloc = [&](size_t bytes) { void* r = p; p += (bytes + 255) & ~(size_t)255; return r; };
    float*    gx_f    = (float*)alloc((size_t)T_LEN * BATCH * G4 * 4);
    float*    gx_b    = (float*)alloc((size_t)T_LEN * BATCH * G4 * 4);
    float*    h_em    = (float*)alloc((size_t)T_LEN * BATCH * 512 * 4);
    float*    x_em    = (float*)alloc((size_t)BATCH * EDIM * HW * 4);
    ushort*   padT    = (ushort*)alloc((size_t)BATCH * PADH * PADW * CDIM * 2);
    ushort*   Wt      = (ushort*)alloc((size_t)9 * EDIM * CDIM * 2);
    ushort*   hen_bf  = (ushort*)alloc((size_t)T_LEN * BATCH * DDIM * 2);
    ushort*   Wihf_bf = (ushort*)alloc((size_t)G4 * DDIM * 2);
    ushort*   Wihb_bf = (ushort*)alloc((size_t)G4 * DDIM * 2);
    ushort*   Whhf_bf = (ushort*)alloc((size_t)G4 * HDIM * 2);
    ushort*   Whhb_bf = (ushort*)alloc((size_t)G4 * HDIM * 2);
    ushort*   Wdec_bf = (ushort*)alloc((size_t)HDIM * 1024 * 2);
    ushort*   Whem_bf = (ushort*)alloc((size_t)EDIM * HDIM * 2);
    ushort*   hs_bf   = (ushort*)alloc((size_t)T_LEN * BATCH * 1024 * 2);
    ushort*   hde_bf  = (ushort*)alloc((size_t)T_LEN * BATCH * 512 * 2);
    unsigned* cnt     = (unsigned*)alloc(256);

    // fused prep: 7 f32->bf16 conversions + zero barrier counter
    PrepArgs pa;
    pa.s[0] = hidden_en; pa.d[0] = hen_bf;
    pa.s[1] = W_ih_f;    pa.d[1] = Wihf_bf;
    pa.s[2] = W_ih_b;    pa.d[2] = Wihb_bf;
    pa.s[3] = W_hh_f;    pa.d[3] = Whhf_bf;
    pa.s[4] = W_hh_b;    pa.d[4] = Whhb_bf;
    pa.s[5] = W_dec;     pa.d[5] = Wdec_bf;
    pa.s[6] = W_hem;     pa.d[6] = Whem_bf;
    fuse_prep<<<5120, 256, 0, stream>>>(pa, cnt);
    zero_padT<<<(BATCH * PADH * PADW * CDIM / 4 + 255) / 256, 256, 0, stream>>>(padT);
    fill_padT<<<dim3(8, 16, 16), 256, 0, stream>>>(conv_f, padT);
    repack_wem<<<(9 * EDIM * CDIM + 255) / 256, 256, 0, stream>>>(W_em, Wt);

    // gx for both directions (bias = b_ih + b_hh folded in); 256 blocks each
    gemm64<<<dim3(32, 8), 256, 0, stream>>>(hen_bf, Wihf_bf, b_ih_f, b_hh_f,
                                            gx_f, nullptr, nullptr, 512, G4, 512);
    gemm64<<<dim3(32, 8), 256, 0, stream>>>(hen_bf, Wihb_bf, b_ih_b, b_hh_b,
                                            gx_b, nullptr, nullptr, 512, G4, 512);

    // conv (independent of LSTM); 512 blocks
    conv64<<<dim3(8, 64), 256, 0, stream>>>(padT, Wt, b_em, x_em);

    // all 32 LSTM steps in one persistent launch
    lstm_persist<<<64, 64, 0, stream>>>(Whhf_bf, Whhb_bf, gx_f, gx_b, hs_bf, cnt);

    // linear decode: bf16 for h_em GEMM + scatter f32 straight into out[:, :, 0:512]
    gemm64<<<dim3(8, 8), 256, 0, stream>>>(hs_bf, Wdec_bf, b_dec, nullptr,
                                           nullptr, hde_bf, out, 512, 512, 1024);

    // h_em
    gemm64<<<dim3(8, 8), 256, 0, stream>>>(hde_bf, Whem_bf, b_hem, nullptr,
                                           h_em, nullptr, nullptr, 512, 512, 512);

    // attention -> out[:, :, 512:]
    attention<<<512, 256, 0, stream>>>(x_em, h_em, w_att, out);
}

// Round 5
// 402.976 us; speedup vs baseline: 4.0831x; 1.1079x over previous
//
#include <hip/hip_runtime.h>
#include <hip/hip_bf16.h>
#include <math.h>

// Dims (fixed by the problem)
#define T_LEN 32
#define BATCH 16
#define DDIM  512
#define HDIM  512
#define EDIM  512
#define CDIM  512
#define FHH   8
#define FWW   32
#define HW    256         // FHH*FWW
#define G4    2048        // 4*HDIM
#define PADH  10
#define PADW  34
#define WLP   520         // padded LDS row stride (ushorts): bank-conflict-free

typedef __attribute__((ext_vector_type(8))) short bf16x8;
typedef __attribute__((ext_vector_type(4))) float f32x4;

// round-to-nearest-even f32 -> bf16 bits
__device__ __forceinline__ ushort bfr(float x) {
    union { float f; uint32_t u; } c; c.f = x;
    uint32_t r = (c.u + 0x7FFFu + ((c.u >> 16) & 1u)) >> 16;
    return (ushort)r;
}

__device__ __forceinline__ float frcp(float x) { return __builtin_amdgcn_rcpf(x); }
__device__ __forceinline__ float ftanh(float x) {
    return 1.f - 2.f * frcp(1.f + __expf(2.f * x));
}
__device__ __forceinline__ float fsig(float x) {
    return frcp(1.f + __expf(-x));
}

__device__ __forceinline__ void ld_lds16(const void* g, void* l) {
    __builtin_amdgcn_global_load_lds((const __attribute__((address_space(1))) void*)g,
                                     (__attribute__((address_space(3))) void*)l, 16, 0, 0);
}

// ---------------------------------------------------------------------------
// Prep kernels
// ---------------------------------------------------------------------------

// zero padT (B,10,34,C) bf16
__global__ void zero_padT(ushort* __restrict__ dst) {
    int i = blockIdx.x * 256 + threadIdx.x;
    const int n = BATCH * PADH * PADW * CDIM / 4;
    if (i < n) ((ushort4*)dst)[i] = make_ushort4(0, 0, 0, 0);
}

// conv_f (B,C,8,32) f32 -> padT (B,10,34,C) bf16, interior only (transpose via LDS)
__global__ __launch_bounds__(256) void fill_padT(const float* __restrict__ src,
                                                 ushort* __restrict__ dst) {
    __shared__ float tile[32][33];
    int s0 = blockIdx.x * 32, c0 = blockIdx.y * 32, b = blockIdx.z;
    int tid = threadIdx.x;
    int lo = tid & 31, hi = tid >> 5;
#pragma unroll
    for (int it = 0; it < 4; ++it) {
        int cl = hi + it * 8;
        tile[cl][lo] = src[((size_t)(b * CDIM + c0 + cl)) * HW + s0 + lo];
    }
    __syncthreads();
#pragma unroll
    for (int it = 0; it < 4; ++it) {
        int sl = hi + it * 8;
        int s = s0 + sl;
        int y = s >> 5, x = s & 31;
        dst[(((size_t)b * PADH + y + 1) * PADW + (x + 1)) * CDIM + c0 + lo] = bfr(tile[lo][sl]);
    }
}

// W_em (E,C,3,3) f32 -> Wt (9,E,C) bf16
__global__ void repack_wem(const float* __restrict__ src, ushort* __restrict__ dst) {
    int idx = blockIdx.x * 256 + threadIdx.x;
    const int total = 9 * EDIM * CDIM;
    if (idx >= total) return;
    int c = idx % CDIM;
    int t = idx / CDIM;
    int e = t % EDIM;
    int tap = t / EDIM;
    int dy = tap / 3, dx = tap % 3;
    dst[idx] = bfr(src[((e * CDIM + c) * 3 + dy) * 3 + dx]);
}

// fused f32->bf16 of 7 tensors + zero the LSTM barrier flags (64 ints)
struct PrepArgs { const float* s[7]; ushort* d[7]; };
__global__ void fuse_prep(PrepArgs a, int* __restrict__ flags) {
    int i = blockIdx.x * 256 + threadIdx.x;
    if (i < 64) flags[i] = 0;
    // chunk counts (float4): hen 65536 | Wihf 262144 | Wihb 262144 |
    //                        Whhf 262144 | Whhb 262144 | Wdec 131072 | Whem 65536
    const int e0 = 65536, e1 = 327680, e2 = 589824, e3 = 851968,
              e4 = 1114112, e5 = 1245184, e6 = 1310720;
    int seg, base;
    if      (i < e0) { seg = 0; base = 0;  }
    else if (i < e1) { seg = 1; base = e0; }
    else if (i < e2) { seg = 2; base = e1; }
    else if (i < e3) { seg = 3; base = e2; }
    else if (i < e4) { seg = 4; base = e3; }
    else if (i < e5) { seg = 5; base = e4; }
    else if (i < e6) { seg = 6; base = e5; }
    else return;
    int li = i - base;
    float4 v = ((const float4*)a.s[seg])[li];
    ushort4 o;
    o.x = bfr(v.x); o.y = bfr(v.y); o.z = bfr(v.z); o.w = bfr(v.w);
    ((ushort4*)a.d[seg])[li] = o;
}

// ---------------------------------------------------------------------------
// bf16 MFMA GEMM, 64x64 tile, BK=32, 256 threads (4 waves, wave-tile 32x32).
// C(M,N) = A(M,K) @ B(N,K)^T + bias0 + bias1.
// Outputs: optional f32 C, optional bf16 Cbf, optional scatter into out
// (decode mapping: row m = t*16+b -> out[(b*32+t)*1024 + n], N must be 512).
// ---------------------------------------------------------------------------
__global__ __launch_bounds__(256) void gemm64(
    const ushort* __restrict__ A, const ushort* __restrict__ B,
    const float* __restrict__ bias0, const float* __restrict__ bias1,
    float* __restrict__ C, ushort* __restrict__ Cbf, float* __restrict__ Cscat,
    int M, int N, int K)
{
    __shared__ ushort As[2048], Bs[2048];
    const int n0 = blockIdx.x * 64, m0 = blockIdx.y * 64;
    const int tid = threadIdx.x, w = tid >> 6, lane = tid & 63;
    const int r0 = tid >> 2, c0 = (tid & 3) * 8;
    const ushort* Ap = A + (size_t)(m0 + r0) * K + c0;
    const ushort* Bp = B + (size_t)(n0 + r0) * K + c0;
    ushort* AsW = &As[w * 512];
    ushort* BsW = &Bs[w * 512];
    const int wm = (w >> 1) * 32, wn = (w & 1) * 32;
    const int kb = (lane >> 4) * 8, fr = lane & 15;
    f32x4 acc[2][2];
#pragma unroll
    for (int i = 0; i < 2; ++i)
#pragma unroll
        for (int j = 0; j < 2; ++j) acc[i][j] = {0.f, 0.f, 0.f, 0.f};
    for (int kk = 0; kk < K; kk += 32) {
        __syncthreads();
        ld_lds16(Ap + kk, AsW);
        ld_lds16(Bp + kk, BsW);
        __syncthreads();
        bf16x8 af[2], bg[2];
#pragma unroll
        for (int i = 0; i < 2; ++i)
            af[i] = *(const bf16x8*)&As[(wm + i * 16 + fr) * 32 + kb];
#pragma unroll
        for (int j = 0; j < 2; ++j)
            bg[j] = *(const bf16x8*)&Bs[(wn + j * 16 + fr) * 32 + kb];
#pragma unroll
        for (int i = 0; i < 2; ++i)
#pragma unroll
            for (int j = 0; j < 2; ++j)
                acc[i][j] = __builtin_amdgcn_mfma_f32_16x16x32_bf16(af[i], bg[j], acc[i][j], 0, 0, 0);
    }
    const int col = lane & 15, rq = (lane >> 4) * 4;
#pragma unroll
    for (int i = 0; i < 2; ++i) {
#pragma unroll
        for (int r = 0; r < 4; ++r) {
            int m = m0 + wm + i * 16 + rq + r;
#pragma unroll
            for (int j = 0; j < 2; ++j) {
                int n = n0 + wn + j * 16 + col;
                float v = acc[i][j][r];
                if (bias0) v += bias0[n];
                if (bias1) v += bias1[n];
                if (C)   C[(size_t)m * N + n] = v;
                if (Cbf) Cbf[(size_t)m * N + n] = bfr(v);
                if (Cscat) {
                    int t = m >> 4, b = m & 15;
                    Cscat[((size_t)(b * T_LEN + t)) * 1024 + n] = v;
                }
            }
        }
    }
}

// ---------------------------------------------------------------------------
// conv_em implicit MFMA GEMM, 64x64 tile. grid (8, 64) = 512 blocks.
// ---------------------------------------------------------------------------
__global__ __launch_bounds__(256) void conv64(
    const ushort* __restrict__ padT, const ushort* __restrict__ Wt,
    const float* __restrict__ bias, float* __restrict__ xem)
{
    __shared__ ushort As[2048], Bs[2048];
    const int n0 = blockIdx.x * 64, m0 = blockIdx.y * 64;
    const int tid = threadIdx.x, w = tid >> 6, lane = tid & 63;
    const int r0 = tid >> 2, c0 = (tid & 3) * 8;
    const int b = m0 >> 8, s0 = m0 & 255, y0 = s0 >> 5;
    const int y = y0 + (r0 >> 5), x = r0 & 31;
    const ushort* Abase = padT + (((size_t)b * PADH + y) * PADW + x) * CDIM + c0;
    const ushort* Bbase = Wt + (size_t)(n0 + r0) * CDIM + c0;
    ushort* AsW = &As[w * 512];
    ushort* BsW = &Bs[w * 512];
    const int wm = (w >> 1) * 32, wn = (w & 1) * 32;
    const int kb = (lane >> 4) * 8, fr = lane & 15;
    f32x4 acc[2][2];
#pragma unroll
    for (int i = 0; i < 2; ++i)
#pragma unroll
        for (int j = 0; j < 2; ++j) acc[i][j] = {0.f, 0.f, 0.f, 0.f};
    for (int tap = 0; tap < 9; ++tap) {
        const int dy = tap / 3, dx = tap % 3;
        const ushort* ap = Abase + ((size_t)dy * PADW + dx) * CDIM;
        const ushort* bp = Bbase + (size_t)tap * EDIM * CDIM;
        for (int kk = 0; kk < CDIM; kk += 32) {
            __syncthreads();
            ld_lds16(ap + kk, AsW);
            ld_lds16(bp + kk, BsW);
            __syncthreads();
            bf16x8 af[2], bg[2];
#pragma unroll
            for (int i = 0; i < 2; ++i)
                af[i] = *(const bf16x8*)&As[(wm + i * 16 + fr) * 32 + kb];
#pragma unroll
            for (int j = 0; j < 2; ++j)
                bg[j] = *(const bf16x8*)&Bs[(wn + j * 16 + fr) * 32 + kb];
#pragma unroll
            for (int i = 0; i < 2; ++i)
#pragma unroll
                for (int j = 0; j < 2; ++j)
                    acc[i][j] = __builtin_amdgcn_mfma_f32_16x16x32_bf16(af[i], bg[j], acc[i][j], 0, 0, 0);
        }
    }
    const int col = lane & 15, rq = (lane >> 4) * 4;
#pragma unroll
    for (int i = 0; i < 2; ++i) {
#pragma unroll
        for (int r = 0; r < 4; ++r) {
            int m = m0 + wm + i * 16 + rq + r;
            int s = m & 255;
#pragma unroll
            for (int j = 0; j < 2; ++j) {
                int e = n0 + wn + j * 16 + col;
                xem[((size_t)b * EDIM + e) * HW + s] = acc[i][j][r] + bias[e];
            }
        }
    }
}

// ---------------------------------------------------------------------------
// Persistent LSTM: 64 blocks x 64 threads, all 32 steps in one launch.
// Barrier = per-block flag stores + per-DIRECTION 32-flag vector poll
// (no atomics, no central counter). W slice in LDS with padded rows
// (WLP=520 ushorts -> bank-conflict-free ds_read_b128).
// ---------------------------------------------------------------------------
__global__ __launch_bounds__(64) void lstm_persist(
    const ushort* __restrict__ Whh_f, const ushort* __restrict__ Whh_b,  // (2048,512) bf16
    const float* __restrict__ gx_f, const float* __restrict__ gx_b,      // (T,B,2048)
    ushort* __restrict__ hs_bf,     // (T,B,1024) bf16
    int* __restrict__ flags)        // 64 ints, pre-zeroed
{
    __shared__ ushort Wl[64 * WLP];   // ~66.5KB
    const int blk = blockIdx.x;
    const int dir = blk >> 5;
    const int j0 = (blk & 31) * 16;
    const int lane = threadIdx.x;
    const ushort* W = dir ? Whh_b : Whh_f;
    const float* gx = dir ? gx_b : gx_f;
    const int fr = lane & 15, kq = lane >> 4;

    // stage W slice: row (g*16+jl) holds W[g*512 + j0 + jl][0:512]
    for (int row = 0; row < 64; ++row) {
        int g = row >> 4, jl = row & 15;
        bf16x8 v = *(const bf16x8*)(W + ((size_t)(g * 512 + j0 + jl)) * 512 + lane * 8);
        *(bf16x8*)&Wl[row * WLP + lane * 8] = v;
    }
    __syncthreads();

    const int j = j0 + fr;
    const int fbase = dir * 32;
    f32x4 cr = {0.f, 0.f, 0.f, 0.f};
    for (int step = 0; step < T_LEN; ++step) {
        const int tcur = dir ? (T_LEN - 1 - step) : step;
        // gx loads are independent of h -- issue first
        float gxv[4][4];
#pragma unroll
        for (int r = 0; r < 4; ++r) {
            const float* gxr = gx + ((size_t)tcur * BATCH + (kq * 4 + r)) * G4 + j;
#pragma unroll
            for (int g = 0; g < 4; ++g) gxv[r][g] = gxr[g * 512];
        }
        f32x4 acc[4];
#pragma unroll
        for (int g = 0; g < 4; ++g) acc[g] = {0.f, 0.f, 0.f, 0.f};
        if (step > 0) {
            const int tprev = dir ? tcur + 1 : tcur - 1;
            const ushort* hp = hs_bf + ((size_t)tprev * BATCH + fr) * 1024 + dir * 512 + kq * 8;
#pragma unroll 4
            for (int kk = 0; kk < 512; kk += 32) {
                bf16x8 a = *(const bf16x8*)(hp + kk);
#pragma unroll
                for (int g = 0; g < 4; ++g) {
                    bf16x8 bb = *(const bf16x8*)&Wl[(g * 16 + fr) * WLP + kq * 8 + kk];
                    acc[g] = __builtin_amdgcn_mfma_f32_16x16x32_bf16(a, bb, acc[g], 0, 0, 0);
                }
            }
        }
        // epilogue: batch = kq*4+r, col j
#pragma unroll
        for (int r = 0; r < 4; ++r) {
            int b = kq * 4 + r;
            float gi = gxv[r][0] + acc[0][r];
            float gf = gxv[r][1] + acc[1][r];
            float gg = gxv[r][2] + acc[2][r];
            float go = gxv[r][3] + acc[3][r];
            float si = fsig(gi), sf = fsig(gf), so = fsig(go);
            float c = sf * cr[r] + si * ftanh(gg);
            cr[r] = c;
            float h = so * ftanh(c);
            hs_bf[((size_t)tcur * BATCH + b) * 1024 + dir * 512 + j] = bfr(h);
        }
        if (step < T_LEN - 1) {
            __threadfence();   // release h stores (agent scope)
            if (lane == 0)
                __hip_atomic_store(&flags[blk], step + 1, __ATOMIC_RELAXED,
                                   __HIP_MEMORY_SCOPE_AGENT);
            const int need = step + 1;
            for (;;) {
                int v = __hip_atomic_load(&flags[fbase + (lane & 31)], __ATOMIC_RELAXED,
                                          __HIP_MEMORY_SCOPE_AGENT);
                if (__all(v >= need)) break;
                __builtin_amdgcn_s_sleep(1);
            }
            __threadfence();   // acquire before reading h
        }
    }
}

// ---------------------------------------------------------------------------
// Attention: one block per (t,b), XCD-swizzled; fast tanh.
// ---------------------------------------------------------------------------
__global__ __launch_bounds__(256) void attention(
    const float* __restrict__ xem,   // (B,E,256)
    const float* __restrict__ hem,   // (T*B,E)
    const float* __restrict__ watt,  // (E)
    float* __restrict__ out) {       // (B,T,1024)
    int i = blockIdx.x;
    int k = i >> 3;
    int b = ((i & 7) << 1) | (k & 1);
    int t = k >> 1;
    int tb = t * 16 + b;
    int tid = threadIdx.x;
    __shared__ float hl[512], wl[512], al[256], red[8];
    for (int q = tid; q < 512; q += 256) { hl[q] = hem[(size_t)tb * 512 + q]; wl[q] = watt[q]; }
    __syncthreads();
    const float* xb = xem + (size_t)b * EDIM * HW;
    float sc = 0.f;
#pragma unroll 4
    for (int e = 0; e < 512; ++e)
        sc += ftanh(xb[(size_t)e * HW + tid] + hl[e]) * wl[e];
    float m = sc;
#pragma unroll
    for (int o = 32; o; o >>= 1) m = fmaxf(m, __shfl_xor(m, o));
    if ((tid & 63) == 0) red[tid >> 6] = m;
    __syncthreads();
    m = fmaxf(fmaxf(red[0], red[1]), fmaxf(red[2], red[3]));
    float ex = __expf(sc - m);
    float s = ex;
#pragma unroll
    for (int o = 32; o; o >>= 1) s += __shfl_xor(s, o);
    if ((tid & 63) == 0) red[4 + (tid >> 6)] = s;
    __syncthreads();
    s = red[4] + red[5] + red[6] + red[7];
    al[tid] = ex * frcp(s);
    __syncthreads();
    float* ob = out + ((size_t)(b * T_LEN + t)) * 1024 + 512;
    for (int eo = 0; eo < 512; eo += 256) {
        int e = eo + tid;
        const float* xr = xb + (size_t)e * HW;
        float acc = 0.f;
#pragma unroll 4
        for (int n = 0; n < 256; n += 4) {
            float4 v = *(const float4*)&xr[n];
            acc += al[n] * v.x + al[n + 1] * v.y + al[n + 2] * v.z + al[n + 3] * v.w;
        }
        ob[e] = acc;
    }
}

// ---------------------------------------------------------------------------
extern "C" void kernel_launch(void* const* d_in, const int* in_sizes, int n_in,
                              void* d_out, int out_size, void* d_ws, size_t ws_size,
                              hipStream_t stream) {
    const float* hidden_en = (const float*)d_in[0];
    const float* conv_f    = (const float*)d_in[1];
    const float* W_ih_f    = (const float*)d_in[2];
    const float* W_hh_f    = (const float*)d_in[3];
    const float* b_ih_f    = (const float*)d_in[4];
    const float* b_hh_f    = (const float*)d_in[5];
    const float* W_ih_b    = (const float*)d_in[6];
    const float* W_hh_b    = (const float*)d_in[7];
    const float* b_ih_b    = (const float*)d_in[8];
    const float* b_hh_b    = (const float*)d_in[9];
    const float* W_dec     = (const float*)d_in[10];
    const float* b_dec     = (const float*)d_in[11];
    const float* W_em      = (const float*)d_in[12];
    const float* b_em      = (const float*)d_in[13];
    const float* W_hem     = (const float*)d_in[14];
    const float* b_hem     = (const float*)d_in[15];
    const float* w_att     = (const float*)d_in[16];
    float* out = (float*)d_out;

    // bump allocator over d_ws (~35 MB)
    char* p = (char*)d_ws;
    auto alloc = [&](size_t bytes) { void* r = p; p += (bytes + 255) & ~(size_t)255; return r; };
    float*    gx_f    = (float*)alloc((size_t)T_LEN * BATCH * G4 * 4);
    float*    gx_b    = (float*)alloc((size_t)T_LEN * BATCH * G4 * 4);
    float*    h_em    = (float*)alloc((size_t)T_LEN * BATCH * 512 * 4);
    float*    x_em    = (float*)alloc((size_t)BATCH * EDIM * HW * 4);
    ushort*   padT    = (ushort*)alloc((size_t)BATCH * PADH * PADW * CDIM * 2);
    ushort*   Wt      = (ushort*)alloc((size_t)9 * EDIM * CDIM * 2);
    ushort*   hen_bf  = (ushort*)alloc((size_t)T_LEN * BATCH * DDIM * 2);
    ushort*   Wihf_bf = (ushort*)alloc((size_t)G4 * DDIM * 2);
    ushort*   Wihb_bf = (ushort*)alloc((size_t)G4 * DDIM * 2);
    ushort*   Whhf_bf = (ushort*)alloc((size_t)G4 * HDIM * 2);
    ushort*   Whhb_bf = (ushort*)alloc((size_t)G4 * HDIM * 2);
    ushort*   Wdec_bf = (ushort*)alloc((size_t)HDIM * 1024 * 2);
    ushort*   Whem_bf = (ushort*)alloc((size_t)EDIM * HDIM * 2);
    ushort*   hs_bf   = (ushort*)alloc((size_t)T_LEN * BATCH * 1024 * 2);
    ushort*   hde_bf  = (ushort*)alloc((size_t)T_LEN * BATCH * 512 * 2);
    int*      flags   = (int*)alloc(256);

    // fused prep: 7 f32->bf16 conversions + zero barrier flags
    PrepArgs pa;
    pa.s[0] = hidden_en; pa.d[0] = hen_bf;
    pa.s[1] = W_ih_f;    pa.d[1] = Wihf_bf;
    pa.s[2] = W_ih_b;    pa.d[2] = Wihb_bf;
    pa.s[3] = W_hh_f;    pa.d[3] = Whhf_bf;
    pa.s[4] = W_hh_b;    pa.d[4] = Whhb_bf;
    pa.s[5] = W_dec;     pa.d[5] = Wdec_bf;
    pa.s[6] = W_hem;     pa.d[6] = Whem_bf;
    fuse_prep<<<5120, 256, 0, stream>>>(pa, flags);
    zero_padT<<<(BATCH * PADH * PADW * CDIM / 4 + 255) / 256, 256, 0, stream>>>(padT);
    fill_padT<<<dim3(8, 16, 16), 256, 0, stream>>>(conv_f, padT);
    repack_wem<<<(9 * EDIM * CDIM + 255) / 256, 256, 0, stream>>>(W_em, Wt);

    // gx for both directions (bias = b_ih + b_hh folded in); 256 blocks each
    gemm64<<<dim3(32, 8), 256, 0, stream>>>(hen_bf, Wihf_bf, b_ih_f, b_hh_f,
                                            gx_f, nullptr, nullptr, 512, G4, 512);
    gemm64<<<dim3(32, 8), 256, 0, stream>>>(hen_bf, Wihb_bf, b_ih_b, b_hh_b,
                                            gx_b, nullptr, nullptr, 512, G4, 512);

    // conv (independent of LSTM); 512 blocks
    conv64<<<dim3(8, 64), 256, 0, stream>>>(padT, Wt, b_em, x_em);

    // all 32 LSTM steps in one persistent launch (flag barrier)
    lstm_persist<<<64, 64, 0, stream>>>(Whhf_bf, Whhb_bf, gx_f, gx_b, hs_bf, flags);

    // linear decode: bf16 for h_em GEMM + scatter f32 straight into out[:, :, 0:512]
    gemm64<<<dim3(8, 8), 256, 0, stream>>>(hs_bf, Wdec_bf, b_dec, nullptr,
                                           nullptr, hde_bf, out, 512, 512, 1024);

    // h_em
    gemm64<<<dim3(8, 8), 256, 0, stream>>>(hde_bf, Whem_bf, b_hem, nullptr,
                                           h_em, nullptr, nullptr, 512, 512, 512);

    // attention -> out[:, :, 512:]
    attention<<<512, 256, 0, stream>>>(x_em, h_em, w_att, out);
}

// Round 6
// 273.385 us; speedup vs baseline: 6.0185x; 1.4740x over previous
//
#include <hip/hip_runtime.h>
#include <hip/hip_bf16.h>
#include <math.h>

// Dims (fixed by the problem)
#define T_LEN 32
#define BATCH 16
#define DDIM  512
#define HDIM  512
#define EDIM  512
#define CDIM  512
#define FHH   8
#define FWW   32
#define HW    256         // FHH*FWW
#define G4    2048        // 4*HDIM
#define PADH  10
#define PADW  34
#define WLP   520         // padded LDS row stride (ushorts)

typedef __attribute__((ext_vector_type(8))) short bf16x8;
typedef __attribute__((ext_vector_type(4))) float f32x4;

// round-to-nearest-even f32 -> bf16 bits
__device__ __forceinline__ ushort bfr(float x) {
    union { float f; uint32_t u; } c; c.f = x;
    uint32_t r = (c.u + 0x7FFFu + ((c.u >> 16) & 1u)) >> 16;
    return (ushort)r;
}

__device__ __forceinline__ float frcp(float x) { return __builtin_amdgcn_rcpf(x); }
__device__ __forceinline__ float ftanh(float x) {
    return 1.f - 2.f * frcp(1.f + __expf(2.f * x));
}
__device__ __forceinline__ float fsig(float x) {
    return frcp(1.f + __expf(-x));
}

__device__ __forceinline__ void ld_lds16(const void* g, void* l) {
    __builtin_amdgcn_global_load_lds((const __attribute__((address_space(1))) void*)g,
                                     (__attribute__((address_space(3))) void*)l, 16, 0, 0);
}

// ---- agent-scope (cross-XCD coherent) accesses: sc1 = read/write Infinity
// Cache directly, no cache-wide wbl2/inv needed -------------------------------
__device__ __forceinline__ void st_u16_sc1(ushort* p, ushort v) {
    asm volatile("global_store_short %0, %1, off sc1" :: "v"(p), "v"((uint)v) : "memory");
}
__device__ __forceinline__ void st_i32_sc1(int* p, int v) {
    asm volatile("global_store_dword %0, %1, off sc1" :: "v"(p), "v"(v) : "memory");
}
__device__ __forceinline__ int ld_i32_sc1(const int* p) {
    int v;
    asm volatile("global_load_dword %0, %1, off sc1\n\ts_waitcnt vmcnt(0)"
                 : "=v"(v) : "v"(p) : "memory");
    return v;
}

// ---------------------------------------------------------------------------
// Prep kernels
// ---------------------------------------------------------------------------

// zero padT (B,10,34,C) bf16
__global__ void zero_padT(ushort* __restrict__ dst) {
    int i = blockIdx.x * 256 + threadIdx.x;
    const int n = BATCH * PADH * PADW * CDIM / 4;
    if (i < n) ((ushort4*)dst)[i] = make_ushort4(0, 0, 0, 0);
}

// conv_f (B,C,8,32) f32 -> padT (B,10,34,C) bf16, interior only (transpose via LDS)
__global__ __launch_bounds__(256) void fill_padT(const float* __restrict__ src,
                                                 ushort* __restrict__ dst) {
    __shared__ float tile[32][33];
    int s0 = blockIdx.x * 32, c0 = blockIdx.y * 32, b = blockIdx.z;
    int tid = threadIdx.x;
    int lo = tid & 31, hi = tid >> 5;
#pragma unroll
    for (int it = 0; it < 4; ++it) {
        int cl = hi + it * 8;
        tile[cl][lo] = src[((size_t)(b * CDIM + c0 + cl)) * HW + s0 + lo];
    }
    __syncthreads();
#pragma unroll
    for (int it = 0; it < 4; ++it) {
        int sl = hi + it * 8;
        int s = s0 + sl;
        int y = s >> 5, x = s & 31;
        dst[(((size_t)b * PADH + y + 1) * PADW + (x + 1)) * CDIM + c0 + lo] = bfr(tile[lo][sl]);
    }
}

// W_em (E,C,3,3) f32 -> Wt (9,E,C) bf16
__global__ void repack_wem(const float* __restrict__ src, ushort* __restrict__ dst) {
    int idx = blockIdx.x * 256 + threadIdx.x;
    const int total = 9 * EDIM * CDIM;
    if (idx >= total) return;
    int c = idx % CDIM;
    int t = idx / CDIM;
    int e = t % EDIM;
    int tap = t / EDIM;
    int dy = tap / 3, dx = tap % 3;
    dst[idx] = bfr(src[((e * CDIM + c) * 3 + dy) * 3 + dx]);
}

// fused f32->bf16 of 7 tensors + zero the LSTM barrier flags (sc1!)
struct PrepArgs { const float* s[7]; ushort* d[7]; };
__global__ void fuse_prep(PrepArgs a, int* __restrict__ flags) {
    int i = blockIdx.x * 256 + threadIdx.x;
    if (i < 64) st_i32_sc1(flags + i, 0);   // MUST be sc1: polled with sc1 loads
    // chunk counts (float4): hen 65536 | Wihf 262144 | Wihb 262144 |
    //                        Whhf 262144 | Whhb 262144 | Wdec 131072 | Whem 65536
    const int e0 = 65536, e1 = 327680, e2 = 589824, e3 = 851968,
              e4 = 1114112, e5 = 1245184, e6 = 1310720;
    int seg, base;
    if      (i < e0) { seg = 0; base = 0;  }
    else if (i < e1) { seg = 1; base = e0; }
    else if (i < e2) { seg = 2; base = e1; }
    else if (i < e3) { seg = 3; base = e2; }
    else if (i < e4) { seg = 4; base = e3; }
    else if (i < e5) { seg = 5; base = e4; }
    else if (i < e6) { seg = 6; base = e5; }
    else return;
    int li = i - base;
    float4 v = ((const float4*)a.s[seg])[li];
    ushort4 o;
    o.x = bfr(v.x); o.y = bfr(v.y); o.z = bfr(v.z); o.w = bfr(v.w);
    ((ushort4*)a.d[seg])[li] = o;
}

// ---------------------------------------------------------------------------
// bf16 MFMA GEMM, 64x64 tile, BK=32, 256 threads (4 waves, wave-tile 32x32).
// C(M,N) = A(M,K) @ B(N,K)^T + bias0 + bias1.
// ---------------------------------------------------------------------------
__global__ __launch_bounds__(256) void gemm64(
    const ushort* __restrict__ A, const ushort* __restrict__ B,
    const float* __restrict__ bias0, const float* __restrict__ bias1,
    float* __restrict__ C, ushort* __restrict__ Cbf, float* __restrict__ Cscat,
    int M, int N, int K)
{
    __shared__ ushort As[2048], Bs[2048];
    const int n0 = blockIdx.x * 64, m0 = blockIdx.y * 64;
    const int tid = threadIdx.x, w = tid >> 6, lane = tid & 63;
    const int r0 = tid >> 2, c0 = (tid & 3) * 8;
    const ushort* Ap = A + (size_t)(m0 + r0) * K + c0;
    const ushort* Bp = B + (size_t)(n0 + r0) * K + c0;
    ushort* AsW = &As[w * 512];
    ushort* BsW = &Bs[w * 512];
    const int wm = (w >> 1) * 32, wn = (w & 1) * 32;
    const int kb = (lane >> 4) * 8, fr = lane & 15;
    f32x4 acc[2][2];
#pragma unroll
    for (int i = 0; i < 2; ++i)
#pragma unroll
        for (int j = 0; j < 2; ++j) acc[i][j] = {0.f, 0.f, 0.f, 0.f};
    for (int kk = 0; kk < K; kk += 32) {
        __syncthreads();
        ld_lds16(Ap + kk, AsW);
        ld_lds16(Bp + kk, BsW);
        __syncthreads();
        bf16x8 af[2], bg[2];
#pragma unroll
        for (int i = 0; i < 2; ++i)
            af[i] = *(const bf16x8*)&As[(wm + i * 16 + fr) * 32 + kb];
#pragma unroll
        for (int j = 0; j < 2; ++j)
            bg[j] = *(const bf16x8*)&Bs[(wn + j * 16 + fr) * 32 + kb];
#pragma unroll
        for (int i = 0; i < 2; ++i)
#pragma unroll
            for (int j = 0; j < 2; ++j)
                acc[i][j] = __builtin_amdgcn_mfma_f32_16x16x32_bf16(af[i], bg[j], acc[i][j], 0, 0, 0);
    }
    const int col = lane & 15, rq = (lane >> 4) * 4;
#pragma unroll
    for (int i = 0; i < 2; ++i) {
#pragma unroll
        for (int r = 0; r < 4; ++r) {
            int m = m0 + wm + i * 16 + rq + r;
#pragma unroll
            for (int j = 0; j < 2; ++j) {
                int n = n0 + wn + j * 16 + col;
                float v = acc[i][j][r];
                if (bias0) v += bias0[n];
                if (bias1) v += bias1[n];
                if (C)   C[(size_t)m * N + n] = v;
                if (Cbf) Cbf[(size_t)m * N + n] = bfr(v);
                if (Cscat) {
                    int t = m >> 4, b = m & 15;
                    Cscat[((size_t)(b * T_LEN + t)) * 1024 + n] = v;
                }
            }
        }
    }
}

// ---------------------------------------------------------------------------
// Fused persistent-LSTM + conv kernel.
// Blocks 0..63: LSTM (dispatched first -> co-resident; sc1 flag barrier).
// Blocks 64..575: conv_em implicit MFMA GEMM 64x64 tiles.
// Shared LDS: lstm uses 64*WLP ushorts; conv aliases first 8KB as As/Bs.
// ---------------------------------------------------------------------------
__global__ __launch_bounds__(256) void lstm_conv(
    const ushort* __restrict__ Whh_f, const ushort* __restrict__ Whh_b,  // (2048,512)
    const float* __restrict__ gx_f, const float* __restrict__ gx_b,      // (T,B,2048)
    ushort* __restrict__ hs_bf,     // (T,B,1024) bf16
    int* __restrict__ flags,        // 64 ints, pre-zeroed via sc1
    const ushort* __restrict__ padT, const ushort* __restrict__ Wt,
    const float* __restrict__ bias_em, float* __restrict__ xem)
{
    __shared__ ushort smem[64 * WLP];
    const int bid = blockIdx.x, tid = threadIdx.x;
    const int w = tid >> 6, lane = tid & 63;

    if (bid < 64) {
        // ======================= LSTM =======================
        const int dir = bid >> 5;
        const int j0 = (bid & 31) * 16;
        const ushort* W = dir ? Whh_b : Whh_f;
        const float* gx = dir ? gx_b : gx_f;
        // stage W slice with all 4 waves: row (g*16+jl) = W[g*512+j0+jl][0:512]
#pragma unroll
        for (int i = 0; i < 16; ++i) {
            int row = w * 16 + i;
            int g = row >> 4, jl = row & 15;
            bf16x8 v = *(const bf16x8*)(W + ((size_t)(g * 512 + j0 + jl)) * 512 + lane * 8);
            *(bf16x8*)&smem[row * WLP + lane * 8] = v;
        }
        __syncthreads();
        if (tid >= 64) return;
        __builtin_amdgcn_s_setprio(1);

        const int fr = lane & 15, kq = lane >> 4;
        const int j = j0 + fr;
        const int fbase = dir * 32;
        const int* fq = &flags[fbase + (lane & 31)];
        f32x4 cr = {0.f, 0.f, 0.f, 0.f};
        for (int step = 0; step < T_LEN; ++step) {
            const int tcur = dir ? (T_LEN - 1 - step) : step;
            // gx loads (independent of h)
            float gxv[4][4];
#pragma unroll
            for (int r = 0; r < 4; ++r) {
                const float* gxr = gx + ((size_t)tcur * BATCH + (kq * 4 + r)) * G4 + j;
#pragma unroll
                for (int g = 0; g < 4; ++g) gxv[r][g] = gxr[g * 512];
            }
            f32x4 acc[4];
#pragma unroll
            for (int g = 0; g < 4; ++g) acc[g] = {0.f, 0.f, 0.f, 0.f};
            if (step > 0) {
                const int tprev = dir ? tcur + 1 : tcur - 1;
                const ushort* hp = hs_bf + ((size_t)tprev * BATCH + fr) * 1024 + dir * 512 + kq * 8;
                bf16x8 hreg[16];
#pragma unroll
                for (int u = 0; u < 16; ++u)
                    asm volatile("global_load_dwordx4 %0, %1, off sc1"
                                 : "=v"(hreg[u]) : "v"(hp + u * 32));
                asm volatile("s_waitcnt vmcnt(0)" ::: "memory");
                __builtin_amdgcn_sched_barrier(0);
#pragma unroll
                for (int u = 0; u < 16; ++u) {
#pragma unroll
                    for (int g = 0; g < 4; ++g) {
                        bf16x8 bb = *(const bf16x8*)&smem[(g * 16 + fr) * WLP + kq * 8 + u * 32];
                        acc[g] = __builtin_amdgcn_mfma_f32_16x16x32_bf16(hreg[u], bb, acc[g], 0, 0, 0);
                    }
                }
            }
            // epilogue: batch = kq*4+r, col j; h stores agent-scope
#pragma unroll
            for (int r = 0; r < 4; ++r) {
                int b = kq * 4 + r;
                float gi = gxv[r][0] + acc[0][r];
                float gf = gxv[r][1] + acc[1][r];
                float gg = gxv[r][2] + acc[2][r];
                float go = gxv[r][3] + acc[3][r];
                float si = fsig(gi), sf = fsig(gf), so = fsig(go);
                float c = sf * cr[r] + si * ftanh(gg);
                cr[r] = c;
                float h = so * ftanh(c);
                st_u16_sc1(hs_bf + ((size_t)tcur * BATCH + b) * 1024 + dir * 512 + j, bfr(h));
            }
            if (step < T_LEN - 1) {
                asm volatile("s_waitcnt vmcnt(0)" ::: "memory");   // h committed to IF$
                if (lane == 0) st_i32_sc1(&flags[bid], step + 1);
                const int need = step + 1;
                for (;;) {
                    int v = ld_i32_sc1(fq);
                    if (__all(v >= need)) break;
                    __builtin_amdgcn_s_sleep(1);
                }
            }
        }
        return;
    }

    // ======================= conv =======================
    ushort* As = smem;
    ushort* Bs = smem + 2048;
    const int cbid = bid - 64;
    const int n0 = (cbid & 7) * 64, m0 = (cbid >> 3) * 64;
    const int r0 = tid >> 2, c0 = (tid & 3) * 8;
    const int b = m0 >> 8, s0 = m0 & 255, y0 = s0 >> 5;
    const int y = y0 + (r0 >> 5), x = r0 & 31;
    const ushort* Abase = padT + (((size_t)b * PADH + y) * PADW + x) * CDIM + c0;
    const ushort* Bbase = Wt + (size_t)(n0 + r0) * CDIM + c0;
    ushort* AsW = &As[w * 512];
    ushort* BsW = &Bs[w * 512];
    const int wm = (w >> 1) * 32, wn = (w & 1) * 32;
    const int kb = (lane >> 4) * 8, fr = lane & 15;
    f32x4 acc[2][2];
#pragma unroll
    for (int i = 0; i < 2; ++i)
#pragma unroll
        for (int j = 0; j < 2; ++j) acc[i][j] = {0.f, 0.f, 0.f, 0.f};
    for (int tap = 0; tap < 9; ++tap) {
        const int dy = tap / 3, dx = tap % 3;
        const ushort* ap = Abase + ((size_t)dy * PADW + dx) * CDIM;
        const ushort* bp = Bbase + (size_t)tap * EDIM * CDIM;
        for (int kk = 0; kk < CDIM; kk += 32) {
            __syncthreads();
            ld_lds16(ap + kk, AsW);
            ld_lds16(bp + kk, BsW);
            __syncthreads();
            bf16x8 af[2], bg[2];
#pragma unroll
            for (int i = 0; i < 2; ++i)
                af[i] = *(const bf16x8*)&As[(wm + i * 16 + fr) * 32 + kb];
#pragma unroll
            for (int j = 0; j < 2; ++j)
                bg[j] = *(const bf16x8*)&Bs[(wn + j * 16 + fr) * 32 + kb];
#pragma unroll
            for (int i = 0; i < 2; ++i)
#pragma unroll
                for (int j = 0; j < 2; ++j)
                    acc[i][j] = __builtin_amdgcn_mfma_f32_16x16x32_bf16(af[i], bg[j], acc[i][j], 0, 0, 0);
        }
    }
    const int col = lane & 15, rq = (lane >> 4) * 4;
#pragma unroll
    for (int i = 0; i < 2; ++i) {
#pragma unroll
        for (int r = 0; r < 4; ++r) {
            int m = m0 + wm + i * 16 + rq + r;
            int s = m & 255;
#pragma unroll
            for (int j = 0; j < 2; ++j) {
                int e = n0 + wn + j * 16 + col;
                xem[((size_t)b * EDIM + e) * HW + s] = acc[i][j][r] + bias_em[e];
            }
        }
    }
}

// ---------------------------------------------------------------------------
// Attention: one block per (t,b), XCD-swizzled; fast tanh.
// ---------------------------------------------------------------------------
__global__ __launch_bounds__(256) void attention(
    const float* __restrict__ xem,   // (B,E,256)
    const float* __restrict__ hem,   // (T*B,E)
    const float* __restrict__ watt,  // (E)
    float* __restrict__ out) {       // (B,T,1024)
    int i = blockIdx.x;
    int k = i >> 3;
    int b = ((i & 7) << 1) | (k & 1);
    int t = k >> 1;
    int tb = t * 16 + b;
    int tid = threadIdx.x;
    __shared__ float hl[512], wl[512], al[256], red[8];
    for (int q = tid; q < 512; q += 256) { hl[q] = hem[(size_t)tb * 512 + q]; wl[q] = watt[q]; }
    __syncthreads();
    const float* xb = xem + (size_t)b * EDIM * HW;
    float sc = 0.f;
#pragma unroll 4
    for (int e = 0; e < 512; ++e)
        sc += ftanh(xb[(size_t)e * HW + tid] + hl[e]) * wl[e];
    float m = sc;
#pragma unroll
    for (int o = 32; o; o >>= 1) m = fmaxf(m, __shfl_xor(m, o));
    if ((tid & 63) == 0) red[tid >> 6] = m;
    __syncthreads();
    m = fmaxf(fmaxf(red[0], red[1]), fmaxf(red[2], red[3]));
    float ex = __expf(sc - m);
    float s = ex;
#pragma unroll
    for (int o = 32; o; o >>= 1) s += __shfl_xor(s, o);
    if ((tid & 63) == 0) red[4 + (tid >> 6)] = s;
    __syncthreads();
    s = red[4] + red[5] + red[6] + red[7];
    al[tid] = ex * frcp(s);
    __syncthreads();
    float* ob = out + ((size_t)(b * T_LEN + t)) * 1024 + 512;
    for (int eo = 0; eo < 512; eo += 256) {
        int e = eo + tid;
        const float* xr = xb + (size_t)e * HW;
        float acc = 0.f;
#pragma unroll 4
        for (int n = 0; n < 256; n += 4) {
            float4 v = *(const float4*)&xr[n];
            acc += al[n] * v.x + al[n + 1] * v.y + al[n + 2] * v.z + al[n + 3] * v.w;
        }
        ob[e] = acc;
    }
}

// ---------------------------------------------------------------------------
extern "C" void kernel_launch(void* const* d_in, const int* in_sizes, int n_in,
                              void* d_out, int out_size, void* d_ws, size_t ws_size,
                              hipStream_t stream) {
    const float* hidden_en = (const float*)d_in[0];
    const float* conv_f    = (const float*)d_in[1];
    const float* W_ih_f    = (const float*)d_in[2];
    const float* W_hh_f    = (const float*)d_in[3];
    const float* b_ih_f    = (const float*)d_in[4];
    const float* b_hh_f    = (const float*)d_in[5];
    const float* W_ih_b    = (const float*)d_in[6];
    const float* W_hh_b    = (const float*)d_in[7];
    const float* b_ih_b    = (const float*)d_in[8];
    const float* b_hh_b    = (const float*)d_in[9];
    const float* W_dec     = (const float*)d_in[10];
    const float* b_dec     = (const float*)d_in[11];
    const float* W_em      = (const float*)d_in[12];
    const float* b_em      = (const float*)d_in[13];
    const float* W_hem     = (const float*)d_in[14];
    const float* b_hem     = (const float*)d_in[15];
    const float* w_att     = (const float*)d_in[16];
    float* out = (float*)d_out;

    // bump allocator over d_ws (~35 MB)
    char* p = (char*)d_ws;
    auto alloc = [&](size_t bytes) { void* r = p; p += (bytes + 255) & ~(size_t)255; return r; };
    float*    gx_f    = (float*)alloc((size_t)T_LEN * BATCH * G4 * 4);
    float*    gx_b    = (float*)alloc((size_t)T_LEN * BATCH * G4 * 4);
    float*    h_em    = (float*)alloc((size_t)T_LEN * BATCH * 512 * 4);
    float*    x_em    = (float*)alloc((size_t)BATCH * EDIM * HW * 4);
    ushort*   padT    = (ushort*)alloc((size_t)BATCH * PADH * PADW * CDIM * 2);
    ushort*   Wt      = (ushort*)alloc((size_t)9 * EDIM * CDIM * 2);
    ushort*   hen_bf  = (ushort*)alloc((size_t)T_LEN * BATCH * DDIM * 2);
    ushort*   Wihf_bf = (ushort*)alloc((size_t)G4 * DDIM * 2);
    ushort*   Wihb_bf = (ushort*)alloc((size_t)G4 * DDIM * 2);
    ushort*   Whhf_bf = (ushort*)alloc((size_t)G4 * HDIM * 2);
    ushort*   Whhb_bf = (ushort*)alloc((size_t)G4 * HDIM * 2);
    ushort*   Wdec_bf = (ushort*)alloc((size_t)HDIM * 1024 * 2);
    ushort*   Whem_bf = (ushort*)alloc((size_t)EDIM * HDIM * 2);
    ushort*   hs_bf   = (ushort*)alloc((size_t)T_LEN * BATCH * 1024 * 2);
    ushort*   hde_bf  = (ushort*)alloc((size_t)T_LEN * BATCH * 512 * 2);
    int*      flags   = (int*)alloc(256);

    // fused prep: 7 f32->bf16 conversions + zero barrier flags (sc1)
    PrepArgs pa;
    pa.s[0] = hidden_en; pa.d[0] = hen_bf;
    pa.s[1] = W_ih_f;    pa.d[1] = Wihf_bf;
    pa.s[2] = W_ih_b;    pa.d[2] = Wihb_bf;
    pa.s[3] = W_hh_f;    pa.d[3] = Whhf_bf;
    pa.s[4] = W_hh_b;    pa.d[4] = Whhb_bf;
    pa.s[5] = W_dec;     pa.d[5] = Wdec_bf;
    pa.s[6] = W_hem;     pa.d[6] = Whem_bf;
    fuse_prep<<<5120, 256, 0, stream>>>(pa, flags);
    zero_padT<<<(BATCH * PADH * PADW * CDIM / 4 + 255) / 256, 256, 0, stream>>>(padT);
    fill_padT<<<dim3(8, 16, 16), 256, 0, stream>>>(conv_f, padT);
    repack_wem<<<(9 * EDIM * CDIM + 255) / 256, 256, 0, stream>>>(W_em, Wt);

    // gx for both directions (bias = b_ih + b_hh folded in); 256 blocks each
    gemm64<<<dim3(32, 8), 256, 0, stream>>>(hen_bf, Wihf_bf, b_ih_f, b_hh_f,
                                            gx_f, nullptr, nullptr, 512, G4, 512);
    gemm64<<<dim3(32, 8), 256, 0, stream>>>(hen_bf, Wihb_bf, b_ih_b, b_hh_b,
                                            gx_b, nullptr, nullptr, 512, G4, 512);

    // fused: 32 LSTM steps (blocks 0..63, sc1 barrier) + conv (blocks 64..575)
    lstm_conv<<<576, 256, 0, stream>>>(Whhf_bf, Whhb_bf, gx_f, gx_b, hs_bf, flags,
                                       padT, Wt, b_em, x_em);

    // linear decode: bf16 for h_em GEMM + scatter f32 straight into out[:, :, 0:512]
    gemm64<<<dim3(8, 8), 256, 0, stream>>>(hs_bf, Wdec_bf, b_dec, nullptr,
                                           nullptr, hde_bf, out, 512, 512, 1024);

    // h_em
    gemm64<<<dim3(8, 8), 256, 0, stream>>>(hde_bf, Whem_bf, b_hem, nullptr,
                                           h_em, nullptr, nullptr, 512, 512, 512);

    // attention -> out[:, :, 512:]
    attention<<<512, 256, 0, stream>>>(x_em, h_em, w_att, out);
}

// Round 7
// 253.146 us; speedup vs baseline: 6.4997x; 1.0800x over previous
//
#include <hip/hip_runtime.h>
#include <hip/hip_bf16.h>
#include <math.h>

// Dims (fixed by the problem)
#define T_LEN 32
#define BATCH 16
#define DDIM  512
#define HDIM  512
#define EDIM  512
#define CDIM  512
#define FHH   8
#define FWW   32
#define HW    256         // FHH*FWW
#define G4    2048        // 4*HDIM
#define PADH  10
#define PADW  34
#define WLP   520         // padded LDS row stride (ushorts)

typedef __attribute__((ext_vector_type(8))) short bf16x8;
typedef __attribute__((ext_vector_type(4))) float f32x4;

// round-to-nearest-even f32 -> bf16 bits
__device__ __forceinline__ ushort bfr(float x) {
    union { float f; uint32_t u; } c; c.f = x;
    uint32_t r = (c.u + 0x7FFFu + ((c.u >> 16) & 1u)) >> 16;
    return (ushort)r;
}

__device__ __forceinline__ float frcp(float x) { return __builtin_amdgcn_rcpf(x); }
__device__ __forceinline__ float ftanh(float x) {
    return 1.f - 2.f * frcp(1.f + __expf(2.f * x));
}
__device__ __forceinline__ float fsig(float x) {
    return frcp(1.f + __expf(-x));
}

__device__ __forceinline__ void ld_lds16(const void* g, void* l) {
    __builtin_amdgcn_global_load_lds((const __attribute__((address_space(1))) void*)g,
                                     (__attribute__((address_space(3))) void*)l, 16, 0, 0);
}

// ---- agent-scope (cross-XCD coherent) accesses via sc1 (MALL-coherent) ----
__device__ __forceinline__ void st_u16_sc1(ushort* p, ushort v) {
    asm volatile("global_store_short %0, %1, off sc1" :: "v"(p), "v"((uint)v) : "memory");
}
__device__ __forceinline__ void st_i32_sc1(int* p, int v) {
    asm volatile("global_store_dword %0, %1, off sc1" :: "v"(p), "v"(v) : "memory");
}
__device__ __forceinline__ void st_f32_sc1(float* p, float v) {
    asm volatile("global_store_dword %0, %1, off sc1" :: "v"(p), "v"(v) : "memory");
}
__device__ __forceinline__ int ld_i32_sc1(const int* p) {
    int v;
    asm volatile("global_load_dword %0, %1, off sc1\n\ts_waitcnt vmcnt(0)"
                 : "=v"(v) : "v"(p) : "memory");
    return v;
}

// ---------------------------------------------------------------------------
// prep_all: one launch for all preprocessing.
//   blocks [0,5120):    f32->bf16 of 7 tensors + zero syncbuf[0..79]
//   blocks [5120,7168): conv_f (B,C,8,32) -> padT (B,10,34,C) bf16 interior
//   blocks [7168,7840): padT border zeros
//   blocks [7840,17056): W_em (E,C,3,3) -> Wt (9,E,C) bf16
// ---------------------------------------------------------------------------
struct PrepArgs { const float* s[7]; ushort* d[7]; };
__global__ __launch_bounds__(256) void prep_all(
    PrepArgs a, int* __restrict__ syncbuf,
    const float* __restrict__ conv_f, ushort* __restrict__ padT,
    const float* __restrict__ W_em, ushort* __restrict__ Wt)
{
    __shared__ float tile[32][33];
    const int bid = blockIdx.x, tid = threadIdx.x;
    if (bid < 5120) {
        int i = bid * 256 + tid;
        if (i < 80) st_i32_sc1(syncbuf + i, 0);   // flags[64] + gcnt[16], sc1
        // chunk counts (float4): hen 65536 | Wihf 262144 | Wihb 262144 |
        //                        Whhf 262144 | Whhb 262144 | Wdec 131072 | Whem 65536
        const int e0 = 65536, e1 = 327680, e2 = 589824, e3 = 851968,
                  e4 = 1114112, e5 = 1245184;
        int seg, base;
        if      (i < e0) { seg = 0; base = 0;  }
        else if (i < e1) { seg = 1; base = e0; }
        else if (i < e2) { seg = 2; base = e1; }
        else if (i < e3) { seg = 3; base = e2; }
        else if (i < e4) { seg = 4; base = e3; }
        else if (i < e5) { seg = 5; base = e4; }
        else             { seg = 6; base = e5; }
        int li = i - base;
        float4 v = ((const float4*)a.s[seg])[li];
        ushort4 o;
        o.x = bfr(v.x); o.y = bfr(v.y); o.z = bfr(v.z); o.w = bfr(v.w);
        ((ushort4*)a.d[seg])[li] = o;
        return;
    }
    if (bid < 7168) {
        int id = bid - 5120;
        int s0 = (id & 7) * 32, c0 = ((id >> 3) & 15) * 32, b = id >> 7;
        int lo = tid & 31, hi = tid >> 5;
#pragma unroll
        for (int it = 0; it < 4; ++it) {
            int cl = hi + it * 8;
            tile[cl][lo] = conv_f[((size_t)(b * CDIM + c0 + cl)) * HW + s0 + lo];
        }
        __syncthreads();
#pragma unroll
        for (int it = 0; it < 4; ++it) {
            int sl = hi + it * 8;
            int s = s0 + sl;
            int y = s >> 5, x = s & 31;
            padT[(((size_t)b * PADH + y + 1) * PADW + (x + 1)) * CDIM + c0 + lo] =
                bfr(tile[lo][sl]);
        }
        return;
    }
    if (bid < 7840) {
        int gid = (bid - 7168) * 256 + tid;        // 0..172031
        int c4 = gid & 127;
        int cellb = gid >> 7;                      // 0..1343
        int cell = cellb % 84;
        int b = cellb / 84;
        int y, x;
        if (cell < 34) { y = 0; x = cell; }
        else if (cell < 68) { y = 9; x = cell - 34; }
        else { int k2 = cell - 68; y = 1 + (k2 >> 1); x = (k2 & 1) ? 33 : 0; }
        ((ushort4*)padT)[(((size_t)b * PADH + y) * PADW + x) * (CDIM / 4) + c4] =
            make_ushort4(0, 0, 0, 0);
        return;
    }
    {
        int gid = (bid - 7840) * 256 + tid;        // 0..2359295
        int c = gid % CDIM;
        int t = gid / CDIM;
        int e = t % EDIM;
        int tap = t / EDIM;
        int dy = tap / 3, dx = tap % 3;
        Wt[gid] = bfr(W_em[((e * CDIM + c) * 3 + dy) * 3 + dx]);
    }
}

// ---------------------------------------------------------------------------
// shared 64x64 MFMA tile compute: acc += A_tile @ B_tile^T over K (stride K
// along rows). Ap0/Bp0 = per-thread row pointers (row m0+tid/4, col (tid%4)*8).
// ---------------------------------------------------------------------------
__device__ __forceinline__ void tile64_compute(
    const ushort* Ap0, const ushort* Bp0, int K,
    ushort* smem, int tid, f32x4 (&acc)[2][2])
{
    ushort* As = smem;
    ushort* Bs = smem + 2048;
    const int w = tid >> 6, lane = tid & 63;
    ushort* AsW = &As[w * 512];
    ushort* BsW = &Bs[w * 512];
    const int wm = (w >> 1) * 32, wn = (w & 1) * 32;
    const int kb = (lane >> 4) * 8, fr = lane & 15;
    for (int kk = 0; kk < K; kk += 32) {
        __syncthreads();
        ld_lds16(Ap0 + kk, AsW);
        ld_lds16(Bp0 + kk, BsW);
        __syncthreads();
        bf16x8 af[2], bg[2];
#pragma unroll
        for (int i = 0; i < 2; ++i)
            af[i] = *(const bf16x8*)&As[(wm + i * 16 + fr) * 32 + kb];
#pragma unroll
        for (int j = 0; j < 2; ++j)
            bg[j] = *(const bf16x8*)&Bs[(wn + j * 16 + fr) * 32 + kb];
#pragma unroll
        for (int i = 0; i < 2; ++i)
#pragma unroll
            for (int j = 0; j < 2; ++j)
                acc[i][j] = __builtin_amdgcn_mfma_f32_16x16x32_bf16(af[i], bg[j], acc[i][j], 0, 0, 0);
    }
}

// ---------------------------------------------------------------------------
// bf16 MFMA GEMM, 64x64 tile (decode / h_em).
// ---------------------------------------------------------------------------
__global__ __launch_bounds__(256) void gemm64(
    const ushort* __restrict__ A, const ushort* __restrict__ B,
    const float* __restrict__ bias0,
    float* __restrict__ C, ushort* __restrict__ Cbf, float* __restrict__ Cscat,
    int M, int N, int K)
{
    __shared__ ushort smem[4096];
    const int n0 = blockIdx.x * 64, m0 = blockIdx.y * 64;
    const int tid = threadIdx.x, w = tid >> 6, lane = tid & 63;
    const int r0 = tid >> 2, c0 = (tid & 3) * 8;
    f32x4 acc[2][2];
#pragma unroll
    for (int i = 0; i < 2; ++i)
#pragma unroll
        for (int j = 0; j < 2; ++j) acc[i][j] = {0.f, 0.f, 0.f, 0.f};
    tile64_compute(A + (size_t)(m0 + r0) * K + c0, B + (size_t)(n0 + r0) * K + c0,
                   K, smem, tid, acc);
    const int wm = (w >> 1) * 32, wn = (w & 1) * 32;
    const int col = lane & 15, rq = (lane >> 4) * 4;
#pragma unroll
    for (int i = 0; i < 2; ++i) {
#pragma unroll
        for (int r = 0; r < 4; ++r) {
            int m = m0 + wm + i * 16 + rq + r;
#pragma unroll
            for (int j = 0; j < 2; ++j) {
                int n = n0 + wn + j * 16 + col;
                float v = acc[i][j][r];
                if (bias0) v += bias0[n];
                if (C)   C[(size_t)m * N + n] = v;
                if (Cbf) Cbf[(size_t)m * N + n] = bfr(v);
                if (Cscat) {
                    int t = m >> 4, b = m & 15;
                    Cscat[((size_t)(b * T_LEN + t)) * 1024 + n] = v;
                }
            }
        }
    }
}

// ---------------------------------------------------------------------------
// Fused persistent kernel:
//   blocks [0,64):     LSTM (dir = bid>>5, j-tile = bid&31); sc1 flag barrier;
//                      waits on per-(dir,mtile) gx counters.
//   blocks [64,576):   gx producers (gx = hen @ W_ih^T + b_ih + b_hh), sc1
//                      stores + atomicAdd gcnt[dir*8+mtile]. dir-1 m-tiles
//                      computed in DESCENDING t order (backward scan order).
//   blocks [576,1088): conv_em implicit MFMA GEMM 64x64 tiles.
// syncbuf: [0..63] = step flags, [64..79] = gx m-tile counters.
// ---------------------------------------------------------------------------
__global__ __launch_bounds__(256) void fused_main(
    const ushort* __restrict__ Whh_f, const ushort* __restrict__ Whh_b,
    float* __restrict__ gx_f, float* __restrict__ gx_b,
    const ushort* __restrict__ hen_bf,
    const ushort* __restrict__ Wih_f, const ushort* __restrict__ Wih_b,
    const float* __restrict__ b_ih_f, const float* __restrict__ b_hh_f,
    const float* __restrict__ b_ih_b, const float* __restrict__ b_hh_b,
    ushort* __restrict__ hs_bf,
    int* __restrict__ syncbuf,
    const ushort* __restrict__ padT, const ushort* __restrict__ Wt,
    const float* __restrict__ bias_em, float* __restrict__ xem)
{
    __shared__ ushort smem[64 * WLP];
    const int bid = blockIdx.x, tid = threadIdx.x;
    const int w = tid >> 6, lane = tid & 63;
    int* flags = syncbuf;
    int* gcnt  = syncbuf + 64;

    if (bid < 64) {
        // ======================= LSTM =======================
        const int dir = bid >> 5;
        const int j0 = (bid & 31) * 16;
        const ushort* W = dir ? Whh_b : Whh_f;
        const float* gx = dir ? gx_b : gx_f;
#pragma unroll
        for (int i = 0; i < 16; ++i) {
            int row = w * 16 + i;
            int g = row >> 4, jl = row & 15;
            bf16x8 v = *(const bf16x8*)(W + ((size_t)(g * 512 + j0 + jl)) * 512 + lane * 8);
            *(bf16x8*)&smem[row * WLP + lane * 8] = v;
        }
        __syncthreads();
        if (tid >= 64) return;
        __builtin_amdgcn_s_setprio(1);

        const int fr = lane & 15, kq = lane >> 4;
        const int j = j0 + fr;
        const int* fq = &flags[dir * 32 + (lane & 31)];
        f32x4 cr = {0.f, 0.f, 0.f, 0.f};
        int mt_done = -1;
        for (int step = 0; step < T_LEN; ++step) {
            const int tcur = dir ? (T_LEN - 1 - step) : step;
            const int mt = tcur >> 2;
            if (mt != mt_done) {           // gx readiness (once per 4 steps)
                const int* gp = &gcnt[dir * 8 + mt];
                for (;;) {
                    int v = ld_i32_sc1(gp);
                    if (v >= 32) break;
                    __builtin_amdgcn_s_sleep(4);
                }
                mt_done = mt;
            }
            // issue gx loads (sc1; producers stored sc1)
            float gxv[4][4];
#pragma unroll
            for (int r = 0; r < 4; ++r) {
                const float* gxr = gx + ((size_t)tcur * BATCH + (kq * 4 + r)) * G4 + j;
#pragma unroll
                for (int g = 0; g < 4; ++g)
                    asm volatile("global_load_dword %0, %1, off sc1"
                                 : "=v"(gxv[r][g]) : "v"(gxr + g * 512));
            }
            f32x4 acc[4];
#pragma unroll
            for (int g = 0; g < 4; ++g) acc[g] = {0.f, 0.f, 0.f, 0.f};
            if (step > 0) {
                const int tprev = dir ? tcur + 1 : tcur - 1;
                const ushort* hp = hs_bf + ((size_t)tprev * BATCH + fr) * 1024 + dir * 512 + kq * 8;
                bf16x8 hreg[16];
#pragma unroll
                for (int u = 0; u < 16; ++u)
                    asm volatile("global_load_dwordx4 %0, %1, off sc1"
                                 : "=v"(hreg[u]) : "v"(hp + u * 32));
                asm volatile("s_waitcnt vmcnt(0)" ::: "memory");
                __builtin_amdgcn_sched_barrier(0);
#pragma unroll
                for (int u = 0; u < 16; ++u) {
#pragma unroll
                    for (int g = 0; g < 4; ++g) {
                        bf16x8 bb = *(const bf16x8*)&smem[(g * 16 + fr) * WLP + kq * 8 + u * 32];
                        acc[g] = __builtin_amdgcn_mfma_f32_16x16x32_bf16(hreg[u], bb, acc[g], 0, 0, 0);
                    }
                }
            } else {
                asm volatile("s_waitcnt vmcnt(0)" ::: "memory");
                __builtin_amdgcn_sched_barrier(0);
            }
            // epilogue: batch = kq*4+r, col j; h stores agent-scope
#pragma unroll
            for (int r = 0; r < 4; ++r) {
                int b = kq * 4 + r;
                float gi = gxv[r][0] + acc[0][r];
                float gf = gxv[r][1] + acc[1][r];
                float gg = gxv[r][2] + acc[2][r];
                float go = gxv[r][3] + acc[3][r];
                float si = fsig(gi), sf = fsig(gf), so = fsig(go);
                float c = sf * cr[r] + si * ftanh(gg);
                cr[r] = c;
                float h = so * ftanh(c);
                st_u16_sc1(hs_bf + ((size_t)tcur * BATCH + b) * 1024 + dir * 512 + j, bfr(h));
            }
            if (step < T_LEN - 1) {
                asm volatile("s_waitcnt vmcnt(0)" ::: "memory");   // h committed
                if (lane == 0) st_i32_sc1(&flags[bid], step + 1);
                const int need = step + 1;
                for (;;) {
                    int v = ld_i32_sc1(fq);
                    if (__all(v >= need)) break;
                    __builtin_amdgcn_s_sleep(1);
                }
            }
        }
        return;
    }

    if (bid < 576) {
        // ======================= gx producers =======================
        const int gi = bid - 64;
        const int dir = gi & 1;
        const int q = gi >> 1;
        const int nt = q & 31;
        const int mt0 = q >> 5;
        const int mtile = dir ? (7 - mt0) : mt0;
        const ushort* Bw = dir ? Wih_b : Wih_f;
        const float* bi0 = dir ? b_ih_b : b_ih_f;
        const float* bi1 = dir ? b_hh_b : b_hh_f;
        float* Cg = dir ? gx_b : gx_f;
        const int m0 = mtile * 64, n0 = nt * 64;
        const int r0 = tid >> 2, c0 = (tid & 3) * 8;
        f32x4 acc[2][2];
#pragma unroll
        for (int i = 0; i < 2; ++i)
#pragma unroll
            for (int j = 0; j < 2; ++j) acc[i][j] = {0.f, 0.f, 0.f, 0.f};
        tile64_compute(hen_bf + (size_t)(m0 + r0) * 512 + c0,
                       Bw + (size_t)(n0 + r0) * 512 + c0, 512, smem, tid, acc);
        const int wm = (w >> 1) * 32, wn = (w & 1) * 32;
        const int col = lane & 15, rq = (lane >> 4) * 4;
#pragma unroll
        for (int i = 0; i < 2; ++i)
#pragma unroll
            for (int r = 0; r < 4; ++r) {
                int m = m0 + wm + i * 16 + rq + r;
#pragma unroll
                for (int j2 = 0; j2 < 2; ++j2) {
                    int n = n0 + wn + j2 * 16 + col;
                    st_f32_sc1(&Cg[(size_t)m * G4 + n], acc[i][j2][r] + bi0[n] + bi1[n]);
                }
            }
        asm volatile("s_waitcnt vmcnt(0)" ::: "memory");
        __syncthreads();
        if (tid == 0) atomicAdd(&gcnt[dir * 8 + mtile], 1);
        return;
    }

    // ======================= conv =======================
    {
        const int cbid = bid - 576;
        const int n0 = (cbid & 7) * 64, m0 = (cbid >> 3) * 64;
        const int r0 = tid >> 2, c0 = (tid & 3) * 8;
        const int b = m0 >> 8, s0 = m0 & 255, y0 = s0 >> 5;
        const int y = y0 + (r0 >> 5), x = r0 & 31;
        const ushort* Abase = padT + (((size_t)b * PADH + y) * PADW + x) * CDIM + c0;
        const ushort* Bbase = Wt + (size_t)(n0 + r0) * CDIM + c0;
        f32x4 acc[2][2];
#pragma unroll
        for (int i = 0; i < 2; ++i)
#pragma unroll
            for (int j = 0; j < 2; ++j) acc[i][j] = {0.f, 0.f, 0.f, 0.f};
        for (int tap = 0; tap < 9; ++tap) {
            const int dy = tap / 3, dx = tap % 3;
            tile64_compute(Abase + ((size_t)dy * PADW + dx) * CDIM,
                           Bbase + (size_t)tap * EDIM * CDIM, 512, smem, tid, acc);
        }
        const int wm = (w >> 1) * 32, wn = (w & 1) * 32;
        const int col = lane & 15, rq = (lane >> 4) * 4;
#pragma unroll
        for (int i = 0; i < 2; ++i)
#pragma unroll
            for (int r = 0; r < 4; ++r) {
                int m = m0 + wm + i * 16 + rq + r;
                int s = m & 255;
#pragma unroll
                for (int j2 = 0; j2 < 2; ++j2) {
                    int e = n0 + wn + j2 * 16 + col;
                    xem[((size_t)b * EDIM + e) * HW + s] = acc[i][j2][r] + bias_em[e];
                }
            }
    }
}

// ---------------------------------------------------------------------------
// Attention: one block per (t,b), XCD-swizzled; fast tanh.
// ---------------------------------------------------------------------------
__global__ __launch_bounds__(256) void attention(
    const float* __restrict__ xem,   // (B,E,256)
    const float* __restrict__ hem,   // (T*B,E)
    const float* __restrict__ watt,  // (E)
    float* __restrict__ out) {       // (B,T,1024)
    int i = blockIdx.x;
    int k = i >> 3;
    int b = ((i & 7) << 1) | (k & 1);
    int t = k >> 1;
    int tb = t * 16 + b;
    int tid = threadIdx.x;
    __shared__ float hl[512], wl[512], al[256], red[8];
    for (int q = tid; q < 512; q += 256) { hl[q] = hem[(size_t)tb * 512 + q]; wl[q] = watt[q]; }
    __syncthreads();
    const float* xb = xem + (size_t)b * EDIM * HW;
    float sc = 0.f;
#pragma unroll 4
    for (int e = 0; e < 512; ++e)
        sc += ftanh(xb[(size_t)e * HW + tid] + hl[e]) * wl[e];
    float m = sc;
#pragma unroll
    for (int o = 32; o; o >>= 1) m = fmaxf(m, __shfl_xor(m, o));
    if ((tid & 63) == 0) red[tid >> 6] = m;
    __syncthreads();
    m = fmaxf(fmaxf(red[0], red[1]), fmaxf(red[2], red[3]));
    float ex = __expf(sc - m);
    float s = ex;
#pragma unroll
    for (int o = 32; o; o >>= 1) s += __shfl_xor(s, o);
    if ((tid & 63) == 0) red[4 + (tid >> 6)] = s;
    __syncthreads();
    s = red[4] + red[5] + red[6] + red[7];
    al[tid] = ex * frcp(s);
    __syncthreads();
    float* ob = out + ((size_t)(b * T_LEN + t)) * 1024 + 512;
    for (int eo = 0; eo < 512; eo += 256) {
        int e = eo + tid;
        const float* xr = xb + (size_t)e * HW;
        float acc = 0.f;
#pragma unroll 4
        for (int n = 0; n < 256; n += 4) {
            float4 v = *(const float4*)&xr[n];
            acc += al[n] * v.x + al[n + 1] * v.y + al[n + 2] * v.z + al[n + 3] * v.w;
        }
        ob[e] = acc;
    }
}

// ---------------------------------------------------------------------------
extern "C" void kernel_launch(void* const* d_in, const int* in_sizes, int n_in,
                              void* d_out, int out_size, void* d_ws, size_t ws_size,
                              hipStream_t stream) {
    const float* hidden_en = (const float*)d_in[0];
    const float* conv_f    = (const float*)d_in[1];
    const float* W_ih_f    = (const float*)d_in[2];
    const float* W_hh_f    = (const float*)d_in[3];
    const float* b_ih_f    = (const float*)d_in[4];
    const float* b_hh_f    = (const float*)d_in[5];
    const float* W_ih_b    = (const float*)d_in[6];
    const float* W_hh_b    = (const float*)d_in[7];
    const float* b_ih_b    = (const float*)d_in[8];
    const float* b_hh_b    = (const float*)d_in[9];
    const float* W_dec     = (const float*)d_in[10];
    const float* b_dec     = (const float*)d_in[11];
    const float* W_em      = (const float*)d_in[12];
    const float* b_em      = (const float*)d_in[13];
    const float* W_hem     = (const float*)d_in[14];
    const float* b_hem     = (const float*)d_in[15];
    const float* w_att     = (const float*)d_in[16];
    float* out = (float*)d_out;

    // bump allocator over d_ws (~35 MB)
    char* p = (char*)d_ws;
    auto alloc = [&](size_t bytes) { void* r = p; p += (bytes + 255) & ~(size_t)255; return r; };
    float*    gx_f    = (float*)alloc((size_t)T_LEN * BATCH * G4 * 4);
    float*    gx_b    = (float*)alloc((size_t)T_LEN * BATCH * G4 * 4);
    float*    h_em    = (float*)alloc((size_t)T_LEN * BATCH * 512 * 4);
    float*    x_em    = (float*)alloc((size_t)BATCH * EDIM * HW * 4);
    ushort*   padT    = (ushort*)alloc((size_t)BATCH * PADH * PADW * CDIM * 2);
    ushort*   Wt      = (ushort*)alloc((size_t)9 * EDIM * CDIM * 2);
    ushort*   hen_bf  = (ushort*)alloc((size_t)T_LEN * BATCH * DDIM * 2);
    ushort*   Wihf_bf = (ushort*)alloc((size_t)G4 * DDIM * 2);
    ushort*   Wihb_bf = (ushort*)alloc((size_t)G4 * DDIM * 2);
    ushort*   Whhf_bf = (ushort*)alloc((size_t)G4 * HDIM * 2);
    ushort*   Whhb_bf = (ushort*)alloc((size_t)G4 * HDIM * 2);
    ushort*   Wdec_bf = (ushort*)alloc((size_t)HDIM * 1024 * 2);
    ushort*   Whem_bf = (ushort*)alloc((size_t)EDIM * HDIM * 2);
    ushort*   hs_bf   = (ushort*)alloc((size_t)T_LEN * BATCH * 1024 * 2);
    ushort*   hde_bf  = (ushort*)alloc((size_t)T_LEN * BATCH * 512 * 2);
    int*      syncbuf = (int*)alloc(512);

    // one prep launch: conversions + padT (zero border + fill) + Wt repack
    PrepArgs pa;
    pa.s[0] = hidden_en; pa.d[0] = hen_bf;
    pa.s[1] = W_ih_f;    pa.d[1] = Wihf_bf;
    pa.s[2] = W_ih_b;    pa.d[2] = Wihb_bf;
    pa.s[3] = W_hh_f;    pa.d[3] = Whhf_bf;
    pa.s[4] = W_hh_b;    pa.d[4] = Whhb_bf;
    pa.s[5] = W_dec;     pa.d[5] = Wdec_bf;
    pa.s[6] = W_hem;     pa.d[6] = Whem_bf;
    prep_all<<<17056, 256, 0, stream>>>(pa, syncbuf, conv_f, padT, W_em, Wt);

    // fused: gx producers + 32 LSTM steps + conv, one persistent launch
    fused_main<<<1088, 256, 0, stream>>>(Whhf_bf, Whhb_bf, gx_f, gx_b, hen_bf,
                                         Wihf_bf, Wihb_bf, b_ih_f, b_hh_f,
                                         b_ih_b, b_hh_b, hs_bf, syncbuf,
                                         padT, Wt, b_em, x_em);

    // linear decode: bf16 copy for h_em + scatter f32 into out[:, :, 0:512]
    gemm64<<<dim3(8, 8), 256, 0, stream>>>(hs_bf, Wdec_bf, b_dec,
                                           nullptr, hde_bf, out, 512, 512, 1024);

    // h_em
    gemm64<<<dim3(8, 8), 256, 0, stream>>>(hde_bf, Whem_bf, b_hem,
                                           h_em, nullptr, nullptr, 512, 512, 512);

    // attention -> out[:, :, 512:]
    attention<<<512, 256, 0, stream>>>(x_em, h_em, w_att, out);
}